// Round 11
// baseline (1161.148 us; speedup 1.0000x reference)
//
#include <hip/hip_runtime.h>
#include <hip/hip_bf16.h>
#include <math.h>

#define N_NODES 50000
#define NOFF    50004   // padded off-array stride (16B-aligned int4 stores)
#define NBLK    49      // ceil(N_NODES/1024) scan blocks per type
#define F_IN    256
#define H       128
#define HEADS   4
#define HH      512   // HEADS*H
#define L_LAYERS 3
#define T_TYPES  3
#define E_EDGES  250000
#define NEG      0.2f

#define GEMM_RB   391            // row blocks: ceil(50000/128)
#define GEMM_GRID (GEMM_RB*8)    // per-type grid, 3128 % 8 == 0

typedef __attribute__((ext_vector_type(8))) short short8_t;   // 8 bf16 (4 VGPRs)
typedef __attribute__((ext_vector_type(4))) float float4_t;
typedef __attribute__((ext_vector_type(2))) float float2_t;

__device__ __forceinline__ float leaky(float x) { return x > 0.f ? x : NEG * x; }

// hardware RNE f32->bf16 (v_cvt_pk_bf16_f32, 1 VALU op)
__device__ __forceinline__ unsigned int cvt_pk_bf16(float lo, float hi) {
    unsigned int d;
    asm("v_cvt_pk_bf16_f32 %0, %1, %2" : "=v"(d) : "v"(lo), "v"(hi));
    return d;
}

__device__ __forceinline__ unsigned short f2bf(float f) {
    return (unsigned short)cvt_pk_bf16(f, f);
}

__device__ __forceinline__ float bf2f(unsigned short u) {
    union { unsigned int i; float f; } v; v.i = ((unsigned)u) << 16; return v.f;
}

// ---- packed fp32 (VOP3P, full-rate on CDNA) ----
__device__ __forceinline__ float2_t pk_add(float2_t a, float2_t b) {
    float2_t d;
    asm("v_pk_add_f32 %0, %1, %2" : "=v"(d) : "v"(a), "v"(b));
    return d;
}
__device__ __forceinline__ float2_t pk_fma(float2_t a, float2_t b, float2_t c) {
    float2_t d;
    asm("v_pk_fma_f32 %0, %1, %2, %3" : "=v"(d) : "v"(a), "v"(b), "v"(c));
    return d;
}
__device__ __forceinline__ float2_t pk_abs(float2_t a) {
    union { float2_t f; unsigned int u[2]; } v; v.f = a;
    v.u[0] &= 0x7fffffffu;
    v.u[1] &= 0x7fffffffu;
    return v.f;
}

// single-instruction 2^x (avoids glibc __exp2f macro collision)
__device__ __forceinline__ float fast_exp2(float x) {
    return __builtin_amdgcn_exp2f(x);
}

// DPP butterfly step: x += dpp_perm(x). Full-rate VALU, no LDS pipe.
template <int CTRL>
__device__ __forceinline__ float dpp_add(float x) {
    union { float f; int i; } a, b;
    a.f = x;
    b.i = __builtin_amdgcn_update_dpp(0, a.i, CTRL, 0xf, 0xf, true);
    return x + b.f;
}
__device__ __forceinline__ float row16_reduce(float p) {
    p = dpp_add<0xB1>(p);    // quad_perm xor1
    p = dpp_add<0x4E>(p);    // quad_perm xor2
    p = dpp_add<0x141>(p);   // row_half_mirror (xor4)
    p = dpp_add<0x140>(p);   // row_mirror (xor8)
    return p;
}

// unpack uint4 (8 bf16) -> 4 packed float2
__device__ __forceinline__ void unpack_pk(uint4 q, float2_t* o) {
    union { unsigned int i; float f; } v;
    float2_t t;
    v.i = q.x << 16;         t.x = v.f;
    v.i = q.x & 0xffff0000u; t.y = v.f; o[0] = t;
    v.i = q.y << 16;         t.x = v.f;
    v.i = q.y & 0xffff0000u; t.y = v.f; o[1] = t;
    v.i = q.z << 16;         t.x = v.f;
    v.i = q.z & 0xffff0000u; t.y = v.f; o[2] = t;
    v.i = q.w << 16;         t.x = v.f;
    v.i = q.w & 0xffff0000u; t.y = v.f; o[3] = t;
}

// ---------------- edge dtype detection: int64 vs int32 layout ----------------
__global__ void detect_kernel(const int* __restrict__ edst, int* __restrict__ flag) {
    __shared__ int s_any;
    if (threadIdx.x == 0) s_any = 0;
    __syncthreads();
    int a = 0;
    #pragma unroll
    for (int j = 0; j < 8; ++j) a |= edst[2 * (threadIdx.x * 8 + j) + 1];
    if (a) atomicOr(&s_any, 1);
    __syncthreads();
    if (threadIdx.x == 0) *flag = s_any ? 0 : 1;  // 1 => int64 layout (stride 2)
}

// ---------------- CSR build ----------------
__global__ void hist_kernel(const int* __restrict__ edst, int* __restrict__ counts,
                            const int* __restrict__ flag) {
    int idx = blockIdx.x * 256 + threadIdx.x;
    if (idx < T_TYPES * E_EDGES) {
        int sh = *flag;
        int t = idx / E_EDGES;
        int d = edst[(size_t)idx << sh];
        if ((unsigned)d < N_NODES)
            atomicAdd(&counts[t * N_NODES + d], 1);
    }
}

// Phase A: per-block partial sums (1024 counts/block, int4-coalesced)
__global__ __launch_bounds__(256) void scan_a_kernel(const int* __restrict__ counts,
                                                     int* __restrict__ bsum) {
    const int b = blockIdx.x;
    const int t = b / NBLK, ch = b % NBLK;
    const int tid = threadIdx.x, lane = tid & 63;
    __shared__ int ws[4];
    const int* cnt = counts + t * N_NODES;
    int i0 = ch * 1024 + tid * 4;
    int s = 0;
    if (i0 + 3 < N_NODES) { int4 v = *(const int4*)(cnt + i0); s = v.x + v.y + v.z + v.w; }
    else { for (int j = 0; j < 4; ++j) { int i = i0 + j; if (i < N_NODES) s += cnt[i]; } }
    #pragma unroll
    for (int o = 32; o > 0; o >>= 1) s += __shfl_xor(s, o);
    if (lane == 0) ws[tid >> 6] = s;
    __syncthreads();
    if (tid == 0) bsum[b] = ws[0] + ws[1] + ws[2] + ws[3];
}

// Phase B: exclusive-scan the 49 block sums per type (tiny, 1 block)
__global__ void scan_b_kernel(int* __restrict__ bsum, int* __restrict__ off) {
    int t = threadIdx.x;
    if (t < T_TYPES) {
        int run = 0;
        for (int c = 0; c < NBLK; ++c) { int v = bsum[t * NBLK + c]; bsum[t * NBLK + c] = run; run += v; }
        off[t * NOFF + N_NODES] = run;
    }
}

// Phase C: block-local exclusive scan + global offset -> off[] and cursor[]
__global__ __launch_bounds__(256) void scan_c_kernel(const int* counts,
                                                     const int* __restrict__ bsum,
                                                     int* __restrict__ off,
                                                     int* cursor) {
    const int b = blockIdx.x;
    const int t = b / NBLK, ch = b % NBLK;
    const int tid = threadIdx.x, lane = tid & 63, w = tid >> 6;
    __shared__ int ws[4];
    const int* cnt = counts + t * N_NODES;
    int i0 = ch * 1024 + tid * 4;
    int v0 = 0, v1 = 0, v2 = 0, v3 = 0;
    if (i0 + 3 < N_NODES) { int4 v = *(const int4*)(cnt + i0); v0 = v.x; v1 = v.y; v2 = v.z; v3 = v.w; }
    else {
        if (i0     < N_NODES) v0 = cnt[i0];
        if (i0 + 1 < N_NODES) v1 = cnt[i0 + 1];
        if (i0 + 2 < N_NODES) v2 = cnt[i0 + 2];
        if (i0 + 3 < N_NODES) v3 = cnt[i0 + 3];
    }
    int s = v0 + v1 + v2 + v3;
    int x = s;
    #pragma unroll
    for (int o = 1; o < 64; o <<= 1) { int y = __shfl_up(x, o); if (lane >= o) x += y; }
    if (lane == 63) ws[w] = x;
    __syncthreads();
    int woff = 0;
    #pragma unroll
    for (int j = 0; j < 4; ++j) woff += (j < w) ? ws[j] : 0;
    int base = bsum[b] + woff + (x - s);
    int e0 = base, e1 = e0 + v0, e2 = e1 + v1, e3 = e2 + v2;
    if (i0 + 3 < N_NODES) {
        *(int4*)(off + t * NOFF + i0)       = make_int4(e0, e1, e2, e3);
        *(int4*)(cursor + t * N_NODES + i0) = make_int4(e0, e1, e2, e3);
    } else {
        if (i0     < N_NODES) { off[t * NOFF + i0]     = e0; cursor[t * N_NODES + i0]     = e0; }
        if (i0 + 1 < N_NODES) { off[t * NOFF + i0 + 1] = e1; cursor[t * N_NODES + i0 + 1] = e1; }
        if (i0 + 2 < N_NODES) { off[t * NOFF + i0 + 2] = e2; cursor[t * N_NODES + i0 + 2] = e2; }
        if (i0 + 3 < N_NODES) { off[t * NOFF + i0 + 3] = e3; cursor[t * N_NODES + i0 + 3] = e3; }
    }
}

__global__ void scatter_kernel(const int* __restrict__ esrc, const int* __restrict__ edst,
                               int* __restrict__ cursor, int* __restrict__ csrc,
                               const int* __restrict__ flag) {
    int idx = blockIdx.x * 256 + threadIdx.x;
    if (idx < T_TYPES * E_EDGES) {
        int sh = *flag;
        int t = idx / E_EDGES;
        int d = edst[(size_t)idx << sh];
        if ((unsigned)d >= N_NODES) return;
        int s = esrc[(size_t)idx << sh];
        if ((unsigned)s >= N_NODES) s = 0;
        int pos = atomicAdd(&cursor[t * N_NODES + d], 1);
        if ((unsigned)pos < E_EDGES)
            csrc[(size_t)t * E_EDGES + pos] = s;
    }
}

// ---------------- weight convert: Wt[lt][c(0..1023)][k] = bf16(W{l,r}[lt][k][c]) -----------
__global__ void wconv_kernel(const float* __restrict__ Wl, const float* __restrict__ Wr,
                             unsigned short* __restrict__ Wt) {
    int idx = blockIdx.x * 256 + threadIdx.x;
    if (idx >= L_LAYERS * T_TYPES * 1024 * H) return;
    int lt  = idx / (1024 * H);
    int rem = idx - lt * (1024 * H);
    int c   = rem / H;
    int k   = rem - c * H;
    float v = (c < HH) ? Wl[(size_t)lt * H * HH + (size_t)k * HH + c]
                       : Wr[(size_t)lt * H * HH + (size_t)k * HH + (c - HH)];
    Wt[idx] = f2bf(v);
}

// feat fp32 [N,256] -> split bf16 fHi/fLo [N,256]
__global__ void featconv_kernel(const float* __restrict__ feat,
                                unsigned short* __restrict__ fHi,
                                unsigned short* __restrict__ fLo) {
    size_t i = ((size_t)blockIdx.x * 256 + threadIdx.x) * 4;
    if (i >= (size_t)N_NODES * F_IN) return;
    float4 v = *(const float4*)(feat + i);
    ushort4 h, l;
    h.x = f2bf(v.x); l.x = f2bf(v.x - bf2f(h.x));
    h.y = f2bf(v.y); l.y = f2bf(v.y - bf2f(h.y));
    h.z = f2bf(v.z); l.z = f2bf(v.z - bf2f(h.z));
    h.w = f2bf(v.w); l.w = f2bf(v.w - bf2f(h.w));
    *(ushort4*)(fHi + i) = h;
    *(ushort4*)(fLo + i) = l;
}

// proj_w [256,128] fp32 -> pWtHi/pWtLo [128 cols][256 k] split-bf16
__global__ void pconv_kernel(const float* __restrict__ pw,
                             unsigned short* __restrict__ pWtHi,
                             unsigned short* __restrict__ pWtLo) {
    int idx = blockIdx.x * 256 + threadIdx.x;
    if (idx >= H * F_IN) return;
    int c = idx / F_IN, k = idx - c * F_IN;
    float v = pw[(size_t)k * H + c];
    unsigned short hi = f2bf(v);
    pWtHi[idx] = hi;
    pWtLo[idx] = f2bf(v - bf2f(hi));
}

// stage a 128x128 bf16 tile (16B chunks, XOR swizzle) -- identical pattern to gemm_mfma
__device__ __forceinline__ void stage_tile(unsigned short* dst, const unsigned short* src,
                                           int rbase, int kbase, int tid, bool guardRows) {
    #pragma unroll
    for (int it = 0; it < 8; ++it) {
        int c = it * 256 + tid;          // 0..2047
        int r = c >> 4, k8 = c & 15;
        int slot = (k8 ^ (r & 15)) * 8;
        uint4 v = make_uint4(0, 0, 0, 0);
        int row = rbase + r;
        if (!guardRows || row < N_NODES)
            v = *(const uint4*)(src + (size_t)row * 256 + kbase + k8 * 8);
        *(uint4*)(dst + r * 128 + slot) = v;
    }
}

// ---------------- init GEMM (split-bf16 MFMA): proj = feat@W fp32 ----
__global__ __launch_bounds__(256) void init_gemm_kernel(
    const unsigned short* __restrict__ fHi, const unsigned short* __restrict__ fLo,
    const unsigned short* __restrict__ pWtHi, const unsigned short* __restrict__ pWtLo,
    float* __restrict__ proj)
{
    __shared__ unsigned short smem[32768];   // As 32K | Bs 32K
    unsigned short* As = smem;
    unsigned short* Bs = smem + 16384;
    const int tid = threadIdx.x;
    const int nb = blockIdx.x * 128;

    const int wv = tid >> 6, lane = tid & 63;
    const int lm = lane & 15, kg = lane >> 4;
    const int wm = (wv & 1) * 64, wn = (wv >> 1) * 64;
    float4_t acc[4][4];
    #pragma unroll
    for (int i = 0; i < 4; ++i)
        #pragma unroll
        for (int j = 0; j < 4; ++j)
            acc[i][j] = (float4_t){0.f, 0.f, 0.f, 0.f};

    auto compute = [&]() {
        #pragma unroll
        for (int ks = 0; ks < 4; ++ks) {
            const int K8 = ks * 4 + kg;
            const int slot = (K8 ^ lm) * 8;
            short8_t a[4], b[4];
            #pragma unroll
            for (int i = 0; i < 4; ++i) {
                a[i] = *(const short8_t*)(As + (wm + i * 16 + lm) * 128 + slot);
                b[i] = *(const short8_t*)(Bs + (wn + i * 16 + lm) * 128 + slot);
            }
            #pragma unroll
            for (int i = 0; i < 4; ++i)
                #pragma unroll
                for (int j = 0; j < 4; ++j)
                    acc[i][j] = __builtin_amdgcn_mfma_f32_16x16x32_bf16(a[i], b[j], acc[i][j], 0, 0, 0);
        }
    };

    #pragma unroll
    for (int kh = 0; kh < 2; ++kh) {
        const int kbase = kh * 128;
        stage_tile(As, fHi, nb, kbase, tid, true);
        stage_tile(Bs, pWtHi, 0, kbase, tid, false);
        __syncthreads();
        compute();
        __syncthreads();
        stage_tile(Bs, pWtLo, 0, kbase, tid, false);
        __syncthreads();
        compute();
        __syncthreads();
        stage_tile(As, fLo, nb, kbase, tid, true);
        stage_tile(Bs, pWtHi, 0, kbase, tid, false);
        __syncthreads();
        compute();
        __syncthreads();
    }

    #pragma unroll
    for (int i = 0; i < 4; ++i) {
        #pragma unroll
        for (int r = 0; r < 4; ++r) {
            int node = nb + wm + i * 16 + kg * 4 + r;
            if (node < N_NODES) {
                #pragma unroll
                for (int j = 0; j < 4; ++j)
                    proj[(size_t)node * H + wn + j * 16 + lm] = acc[i][j][r];
            }
        }
    }
}

// ---------------- LN + combine: x0 = 0.7*leaky(LN(proj+b)) + 0.5*l2n(emb)
__global__ __launch_bounds__(128) void ln_combine_kernel(
    const float* __restrict__ proj, const float* __restrict__ emb,
    const float* __restrict__ pb, const float* __restrict__ g, const float* __restrict__ b,
    float* __restrict__ x0, unsigned short* __restrict__ xcurb)
{
    __shared__ float s0[2], s1[2];
    const int tid = threadIdx.x;
    const int nb = blockIdx.x * 8;
    const int c = tid;
    float acc[8];
    #pragma unroll
    for (int nn = 0; nn < 8; ++nn) {
        int node = nb + nn;
        acc[nn] = (node < N_NODES) ? proj[(size_t)node * H + c] : 0.f;
    }
    const float pbc = pb[c], gc = g[c], bc = b[c];
    for (int nn = 0; nn < 8; ++nn) {
        float v = acc[nn] + pbc;
        float sum = v, sq = v * v;
        for (int o = 32; o > 0; o >>= 1) { sum += __shfl_down(sum, o); sq += __shfl_down(sq, o); }
        if ((tid & 63) == 0) { s0[tid >> 6] = sum; s1[tid >> 6] = sq; }
        __syncthreads();
        float tot = s0[0] + s0[1], tq = s1[0] + s1[1];
        __syncthreads();
        float mu = tot * (1.f / H);
        float var = tq * (1.f / H) - mu * mu;
        acc[nn] = leaky((v - mu) * rsqrtf(var + 1e-5f) * gc + bc);
    }
    for (int nn = 0; nn < 8; ++nn) {
        int node = nb + nn;
        float ev = (node < N_NODES) ? emb[(size_t)node * H + c] : 0.f;
        float sq = ev * ev;
        for (int o = 32; o > 0; o >>= 1) sq += __shfl_down(sq, o);
        if ((tid & 63) == 0) s0[tid >> 6] = sq;
        __syncthreads();
        float nrm = sqrtf(s0[0] + s0[1]);
        __syncthreads();
        float nev = ev / fmaxf(nrm, 1e-12f);
        float xv = 0.7f * acc[nn] + 0.5f * nev;
        if (node < N_NODES) {
            x0[(size_t)node * H + c] = xv;
            xcurb[(size_t)node * H + c] = f2bf(xv);
        }
    }
}

// ---------------- GEMM core: one 128x128 tile (row nb, col tile colb of type's 1024) -------
__device__ __forceinline__ void gemm_tile_body(
    const unsigned short* __restrict__ x, const unsigned short* __restrict__ Wtt,
    unsigned short* __restrict__ XLt, unsigned short* __restrict__ XRt,
    int nb, int colb, int tid)
{
    __shared__ unsigned short smem[32768];
    unsigned short* As = smem;
    unsigned short* Bs = smem + 16384;
    const int cb = colb * 128;

    #pragma unroll
    for (int it = 0; it < 8; ++it) {
        int c = it * 256 + tid;
        int r = c >> 4;
        int k8 = c & 15;
        int slot = (k8 ^ (r & 15)) * 8;
        int node = nb + r;
        uint4 va = make_uint4(0, 0, 0, 0);
        if (node < N_NODES) va = *(const uint4*)(x + (size_t)node * H + k8 * 8);
        *(uint4*)(As + r * H + slot) = va;
        uint4 vb = *(const uint4*)(Wtt + (size_t)(cb + r) * H + k8 * 8);
        *(uint4*)(Bs + r * H + slot) = vb;
    }
    __syncthreads();

    const int wv = tid >> 6, lane = tid & 63;
    const int lm = lane & 15, kg = lane >> 4;
    const int wm = (wv & 1) * 64, wn = (wv >> 1) * 64;
    float4_t acc[4][4];
    #pragma unroll
    for (int i = 0; i < 4; ++i)
        #pragma unroll
        for (int j = 0; j < 4; ++j)
            acc[i][j] = (float4_t){0.f, 0.f, 0.f, 0.f};

    #pragma unroll
    for (int ks = 0; ks < 4; ++ks) {
        const int K8 = ks * 4 + kg;
        const int slot = (K8 ^ lm) * 8;
        short8_t a[4], b[4];
        #pragma unroll
        for (int i = 0; i < 4; ++i) {
            a[i] = *(const short8_t*)(As + (wm + i * 16 + lm) * H + slot);
            b[i] = *(const short8_t*)(Bs + (wn + i * 16 + lm) * H + slot);
        }
        #pragma unroll
        for (int i = 0; i < 4; ++i)
            #pragma unroll
            for (int j = 0; j < 4; ++j)
                acc[i][j] = __builtin_amdgcn_mfma_f32_16x16x32_bf16(a[i], b[j], acc[i][j], 0, 0, 0);
    }
    __syncthreads();

    unsigned short* Cs = smem;
    #pragma unroll
    for (int i = 0; i < 4; ++i) {
        int row0 = wm + i * 16 + kg * 4;
        #pragma unroll
        for (int j = 0; j < 4; ++j) {
            int col = wn + j * 16 + lm;
            #pragma unroll
            for (int r = 0; r < 4; ++r)
                Cs[(row0 + r) * 136 + col] = f2bf(acc[i][j][r]);
        }
    }
    __syncthreads();

    unsigned short* O = (colb < 4) ? XLt : XRt;
    const int cbase = (colb < 4) ? cb : cb - HH;
    #pragma unroll
    for (int it = 0; it < 8; ++it) {
        int c = it * 256 + tid;
        int r = c >> 4, k8 = (c & 15) * 8;
        int node = nb + r;
        if (node < N_NODES)
            *(uint4*)(O + (size_t)node * HH + cbase + k8) = *(const uint4*)(Cs + r * 136 + k8);
    }
}

// per-type GEMM (XCD-chunked swizzle, proven R9)
__global__ __launch_bounds__(256) void gemm_mfma_kernel(
    const unsigned short* __restrict__ x, const unsigned short* __restrict__ Wt,
    unsigned short* __restrict__ XL, unsigned short* __restrict__ XR)
{
    const int f    = blockIdx.x;
    const int g    = (f % 8) * GEMM_RB + (f / 8);
    const int rowb = g >> 3;
    const int colb = g & 7;
    gemm_tile_body(x, Wt, XL, XR, rowb * 128, colb, threadIdx.x);
}

// fused nt-type GEMM: grid = GEMM_RB*nt*8, bijective XCD chunking
__global__ __launch_bounds__(256) void gemm_mfma_fusedN_kernel(
    const unsigned short* __restrict__ x,
    const unsigned short* __restrict__ Wt_l,   // layer base: nt x 1024 x 128
    unsigned short* __restrict__ XLall, unsigned short* __restrict__ XRall, int nt)
{
    const int f    = blockIdx.x;
    const int per  = GEMM_RB * nt;
    const int g    = (f % 8) * per + (f / 8);
    const int ct   = nt * 8;
    const int rowb = g / ct;
    const int cc   = g % ct;
    const int type = cc >> 3;
    const int colb = cc & 7;
    const unsigned short* Wtt = Wt_l + (size_t)type * 1024 * H;
    unsigned short* XLt = XLall + (size_t)type * N_NODES * HH;
    unsigned short* XRt = XRall + (size_t)type * N_NODES * HH;
    gemm_tile_body(x, Wtt, XLt, XRt, rowb * 128, colb, threadIdx.x);
}

// ---------------- aggregate inner loop (one type) -> acc2 scaled by 1/den into s2 ----------
__device__ __forceinline__ void agg_one_type(
    const unsigned short* __restrict__ XL, const unsigned short* __restrict__ XR,
    const float* __restrict__ att_t, const int* __restrict__ off, const int* __restrict__ csrc,
    int d, int jb, float2_t* s2)
{
    const float L2E = 1.4426950408889634f;
    float2_t rv[4], c1[4], c2[4], acc2[4];
    {
        uint4 q = *(const uint4*)(XR + (size_t)d * HH + jb);
        unpack_pk(q, rv);
        float4 u0 = *(const float4*)(att_t + jb);
        float4 u1 = *(const float4*)(att_t + jb + 4);
        float av[8] = {u0.x, u0.y, u0.z, u0.w, u1.x, u1.y, u1.z, u1.w};
        #pragma unroll
        for (int u = 0; u < 4; ++u) {
            c1[u] = (float2_t){0.6f * L2E * av[2 * u], 0.6f * L2E * av[2 * u + 1]};
            c2[u] = (float2_t){0.4f * L2E * av[2 * u], 0.4f * L2E * av[2 * u + 1]};
            acc2[u] = (float2_t){0.f, 0.f};
        }
    }
    float den = 0.f;

    const int e0 = off[d];
    const int cnt = off[d + 1] - e0;

    uint4 q0 = make_uint4(0, 0, 0, 0), q1 = q0;
    unsigned s2i = 0, s3i = 0;
    if (cnt > 0) q0 = *(const uint4*)(XL + (size_t)((unsigned)csrc[e0])     * HH + jb);
    if (cnt > 1) q1 = *(const uint4*)(XL + (size_t)((unsigned)csrc[e0 + 1]) * HH + jb);
    if (cnt > 2) s2i = (unsigned)csrc[e0 + 2];
    if (cnt > 3) s3i = (unsigned)csrc[e0 + 3];

    int e = 0;
    for (; e + 1 < cnt; e += 2) {
        float2_t lv0[4], lv1[4];
        unpack_pk(q0, lv0);
        unpack_pk(q1, lv1);
        if (e + 2 < cnt) q0 = *(const uint4*)(XL + (size_t)s2i * HH + jb);
        if (e + 3 < cnt) q1 = *(const uint4*)(XL + (size_t)s3i * HH + jb);
        if (e + 4 < cnt) s2i = (unsigned)csrc[e0 + e + 4];
        if (e + 5 < cnt) s3i = (unsigned)csrc[e0 + e + 5];

        float2_t p20 = (float2_t){0.f, 0.f};
        float2_t p21 = (float2_t){0.f, 0.f};
        #pragma unroll
        for (int u = 0; u < 4; ++u) {
            float2_t m0 = pk_add(lv0[u], rv[u]);
            float2_t m1 = pk_add(lv1[u], rv[u]);
            float2_t a0 = pk_abs(m0);
            float2_t a1 = pk_abs(m1);
            p20 = pk_fma(c1[u], m0, p20);
            p21 = pk_fma(c1[u], m1, p21);
            p20 = pk_fma(c2[u], a0, p20);
            p21 = pk_fma(c2[u], a1, p21);
        }
        float p0 = row16_reduce(p20.x + p20.y);
        float p1 = row16_reduce(p21.x + p21.y);
        float w0 = fast_exp2(p0);
        float w1 = fast_exp2(p1);
        den += w0 + w1;
        float2_t w20 = (float2_t){w0, w0};
        float2_t w21 = (float2_t){w1, w1};
        #pragma unroll
        for (int u = 0; u < 4; ++u) {
            acc2[u] = pk_fma(w20, lv0[u], acc2[u]);
            acc2[u] = pk_fma(w21, lv1[u], acc2[u]);
        }
    }
    if (e < cnt) {
        float2_t lv0[4];
        unpack_pk(q0, lv0);
        float2_t p20 = (float2_t){0.f, 0.f};
        #pragma unroll
        for (int u = 0; u < 4; ++u) {
            float2_t m0 = pk_add(lv0[u], rv[u]);
            float2_t a0 = pk_abs(m0);
            p20 = pk_fma(c1[u], m0, p20);
            p20 = pk_fma(c2[u], a0, p20);
        }
        float p0 = row16_reduce(p20.x + p20.y);
        float w0 = fast_exp2(p0);
        den += w0;
        float2_t w20 = (float2_t){w0, w0};
        #pragma unroll
        for (int u = 0; u < 4; ++u) acc2[u] = pk_fma(w20, lv0[u], acc2[u]);
    }

    float inv = 1.f / (den + 1e-16f);
    float2_t inv2 = (float2_t){inv, inv};
    #pragma unroll
    for (int u = 0; u < 4; ++u) s2[u] = pk_fma(inv2, acc2[u], s2[u]);
}

// ---------------- generalized aggregate: ntypes in-register, optional partial rd/wr -------
// rdPartial: add xacc[d] before continuing. wrPartial: store to xacc and stop.
// !wrPartial: apply fused layer epilogue (leaky((sum)/3) + sw*x0 -> out or xcurb).
__global__ __launch_bounds__(64) void aggregate_fusedN_kernel(
    const unsigned short* __restrict__ XLall, const unsigned short* __restrict__ XRall,
    const float* __restrict__ att_b, const float* __restrict__ bias_b,
    const int* __restrict__ off_b, const int* __restrict__ csrc_b,
    int ntypes, int rdPartial, int wrPartial,
    float* __restrict__ xacc,
    const float* __restrict__ x0, const float* __restrict__ skipw,
    int li, int last, unsigned short* __restrict__ xcurb, float* __restrict__ out)
{
    const int lane = threadIdx.x;
    const int d = blockIdx.x;
    if (d >= N_NODES) return;
    const int jb = lane * 8;

    float2_t s2[4];
    #pragma unroll
    for (int u = 0; u < 4; ++u) s2[u] = (float2_t){0.f, 0.f};

    for (int t = 0; t < ntypes; ++t) {
        agg_one_type(XLall + (size_t)t * N_NODES * HH,
                     XRall + (size_t)t * N_NODES * HH,
                     att_b + (size_t)t * HH,
                     off_b + (size_t)t * NOFF,
                     csrc_b + (size_t)t * E_EDGES,
                     d, jb, s2);
    }

    float o[8];
    #pragma unroll
    for (int u = 0; u < 4; ++u) { o[2 * u] = s2[u].x; o[2 * u + 1] = s2[u].y; }
    #pragma unroll
    for (int u = 0; u < 8; ++u) {
        float v = o[u];
        v += __shfl_xor(v, 16);
        v += __shfl_xor(v, 32);
        o[u] = v * 0.25f;       // head mean
    }
    if (lane < 16) {
        // bias for the types processed in this dispatch
        #pragma unroll
        for (int u = 0; u < 8; ++u) {
            float bs = 0.f;
            for (int t = 0; t < ntypes; ++t) bs += bias_b[t * H + jb + u];
            o[u] += bs;
        }
        float* dst = xacc + (size_t)d * H + jb;
        if (rdPartial) {
            float4 c0 = *(const float4*)dst, c1v = *(const float4*)(dst + 4);
            o[0] += c0.x;  o[1] += c0.y;  o[2] += c0.z;  o[3] += c0.w;
            o[4] += c1v.x; o[5] += c1v.y; o[6] += c1v.z; o[7] += c1v.w;
        }
        if (wrPartial) {
            *(float4*)dst       = make_float4(o[0], o[1], o[2], o[3]);
            *(float4*)(dst + 4) = make_float4(o[4], o[5], o[6], o[7]);
        } else {
            const float sw = 1.f / (1.f + __expf(-skipw[li]));
            const float* z = x0 + (size_t)d * H + jb;
            float4 z0 = *(const float4*)z, z1 = *(const float4*)(z + 4);
            float zc[8] = {z0.x, z0.y, z0.z, z0.w, z1.x, z1.y, z1.z, z1.w};
            float r[8];
            #pragma unroll
            for (int u = 0; u < 8; ++u)
                r[u] = leaky(o[u] * (1.f / 3.f)) + sw * zc[u];
            if (last) {
                float* op = out + (size_t)d * H + jb;
                *(float4*)op       = make_float4(r[0], r[1], r[2], r[3]);
                *(float4*)(op + 4) = make_float4(r[4], r[5], r[6], r[7]);
            } else {
                unsigned int w0 = cvt_pk_bf16(r[0], r[1]);
                unsigned int w1 = cvt_pk_bf16(r[2], r[3]);
                unsigned int w2 = cvt_pk_bf16(r[4], r[5]);
                unsigned int w3 = cvt_pk_bf16(r[6], r[7]);
                *(uint4*)(xcurb + (size_t)d * H + jb) = make_uint4(w0, w1, w2, w3);
            }
        }
    }
}

extern "C" void kernel_launch(void* const* d_in, const int* in_sizes, int n_in,
                              void* d_out, int out_size, void* d_ws, size_t ws_size,
                              hipStream_t stream)
{
    const float* feat   = (const float*)d_in[0];
    const float* emb    = (const float*)d_in[1];
    const float* proj_w = (const float*)d_in[2];
    const float* proj_b = (const float*)d_in[3];
    const float* ln_g   = (const float*)d_in[4];
    const float* ln_b   = (const float*)d_in[5];
    const float* skip_w = (const float*)d_in[6];
    const float* Wl     = (const float*)d_in[7];
    const float* Wr     = (const float*)d_in[8];
    const float* att    = (const float*)d_in[9];
    const float* bias   = (const float*)d_in[10];
    const int*   esrc   = (const int*)d_in[11];
    const int*   edst   = (const int*)d_in[12];
    float* out = (float*)d_out;

    // exact workspace requirement for npair XL/XR pairs (mirrors the allocator below)
    auto total_for = [](int npair) -> size_t {
        size_t s = 0;
        auto add = [&](size_t b) { s += (b + 255) & ~(size_t)255; };
        add((size_t)N_NODES * H * 4);                    // x0
        add((size_t)N_NODES * H * 2);                    // xcurb
        add((size_t)npair * N_NODES * HH * 2);           // XL
        add((size_t)npair * N_NODES * HH * 2);           // XR
        add((size_t)L_LAYERS * T_TYPES * 1024 * H * 2);  // Wt
        add((size_t)H * F_IN * 2);                       // pWtHi
        add((size_t)H * F_IN * 2);                       // pWtLo
        add((size_t)T_TYPES * NOFF * 4);                 // off
        add((size_t)T_TYPES * N_NODES * 4);              // cursor
        add((size_t)T_TYPES * E_EDGES * 4);              // csrc
        add((size_t)T_TYPES * NBLK * 4);                 // bsum
        add(256);                                        // eflag
        return s;
    };
    const int NPAIR = (ws_size >= total_for(3)) ? 3 : (ws_size >= total_for(2)) ? 2 : 1;

    char* p = (char*)d_ws;
    auto alloc = [&](size_t bytes) -> char* {
        char* r = p; p += (bytes + 255) & ~(size_t)255; return r;
    };
    float* x0             = (float*)alloc((size_t)N_NODES * H * 4);
    unsigned short* xcurb = (unsigned short*)alloc((size_t)N_NODES * H * 2);
    unsigned short* XL    = (unsigned short*)alloc((size_t)NPAIR * N_NODES * HH * 2);
    unsigned short* XR    = (unsigned short*)alloc((size_t)NPAIR * N_NODES * HH * 2);
    unsigned short* Wt    = (unsigned short*)alloc((size_t)L_LAYERS * T_TYPES * 1024 * H * 2);
    unsigned short* pWtHi = (unsigned short*)alloc((size_t)H * F_IN * 2);
    unsigned short* pWtLo = (unsigned short*)alloc((size_t)H * F_IN * 2);
    int* off    = (int*)alloc((size_t)T_TYPES * NOFF * 4);
    int* cursor = (int*)alloc((size_t)T_TYPES * N_NODES * 4);
    int* csrc   = (int*)alloc((size_t)T_TYPES * E_EDGES * 4);
    int* bsum   = (int*)alloc((size_t)T_TYPES * NBLK * 4);
    int* eflag  = (int*)alloc(256);
    float* xacc = out;  // partial accumulator aliases d_out (free until final epilogue)

    // init-phase scratch aliases the (still-dead) XL/XR regions
    float* proj          = (float*)XL;                                   // 25.6 MB <= 51.2*NPAIR
    unsigned short* fHi  = XR;                                           // 25.6 MB
    unsigned short* fLo  = XR + (size_t)N_NODES * F_IN;                  // 25.6 MB (<= 51.2*NPAIR)

    detect_kernel<<<1, 256, 0, stream>>>(edst, eflag);
    hipMemsetAsync(cursor, 0, (size_t)T_TYPES * N_NODES * 4, stream);
    hist_kernel<<<(T_TYPES * E_EDGES + 255) / 256, 256, 0, stream>>>(edst, cursor, eflag);
    scan_a_kernel<<<T_TYPES * NBLK, 256, 0, stream>>>(cursor, bsum);
    scan_b_kernel<<<1, 256, 0, stream>>>(bsum, off);
    scan_c_kernel<<<T_TYPES * NBLK, 256, 0, stream>>>(cursor, bsum, off, cursor);
    scatter_kernel<<<(T_TYPES * E_EDGES + 255) / 256, 256, 0, stream>>>(esrc, edst, cursor, csrc, eflag);

    wconv_kernel<<<(L_LAYERS * T_TYPES * 1024 * H + 255) / 256, 256, 0, stream>>>(Wl, Wr, Wt);
    featconv_kernel<<<((N_NODES * F_IN / 4) + 255) / 256, 256, 0, stream>>>(feat, fHi, fLo);
    pconv_kernel<<<(H * F_IN + 255) / 256, 256, 0, stream>>>(proj_w, pWtHi, pWtLo);
    init_gemm_kernel<<<(N_NODES + 127) / 128, 256, 0, stream>>>(fHi, fLo, pWtHi, pWtLo, proj);
    ln_combine_kernel<<<N_NODES / 8, 128, 0, stream>>>(proj, emb, proj_b, ln_g, ln_b, x0, xcurb);

    for (int i = 0; i < L_LAYERS; ++i) {
        const unsigned short* wt_l = Wt + (size_t)i * T_TYPES * 1024 * H;
        const float* at_l = att + (size_t)i * T_TYPES * HEADS * H;
        const float* bi_l = bias + (size_t)i * T_TYPES * H;
        const int lastL = (i == L_LAYERS - 1) ? 1 : 0;

        if (NPAIR == 3) {
            gemm_mfma_fusedN_kernel<<<GEMM_RB * 3 * 8, 256, 0, stream>>>(xcurb, wt_l, XL, XR, 3);
            aggregate_fusedN_kernel<<<N_NODES, 64, 0, stream>>>(
                XL, XR, at_l, bi_l, off, csrc, 3, 0, 0, xacc, x0, skip_w, i, lastL, xcurb, out);
        } else if (NPAIR == 2) {
            // types 0,1 fused into pairs 0,1; partial write
            gemm_mfma_fusedN_kernel<<<GEMM_RB * 2 * 8, 256, 0, stream>>>(xcurb, wt_l, XL, XR, 2);
            aggregate_fusedN_kernel<<<N_NODES, 64, 0, stream>>>(
                XL, XR, at_l, bi_l, off, csrc, 2, 0, 1, xacc, x0, skip_w, i, lastL, xcurb, out);
            // type 2 into pair 0; partial read + epilogue
            gemm_mfma_kernel<<<GEMM_GRID, 256, 0, stream>>>(xcurb, wt_l + (size_t)2 * 1024 * H, XL, XR);
            aggregate_fusedN_kernel<<<N_NODES, 64, 0, stream>>>(
                XL, XR, at_l + 2 * HH, bi_l + 2 * H, off + 2 * NOFF, csrc + (size_t)2 * E_EDGES,
                1, 1, 0, xacc, x0, skip_w, i, lastL, xcurb, out);
        } else {
            for (int t = 0; t < T_TYPES; ++t) {
                gemm_mfma_kernel<<<GEMM_GRID, 256, 0, stream>>>(
                    xcurb, wt_l + (size_t)t * 1024 * H, XL, XR);
                aggregate_fusedN_kernel<<<N_NODES, 64, 0, stream>>>(
                    XL, XR, at_l + t * HH, bi_l + t * H, off + t * NOFF, csrc + (size_t)t * E_EDGES,
                    1, (t > 0) ? 1 : 0, (t < T_TYPES - 1) ? 1 : 0,
                    xacc, x0, skip_w, i, lastL, xcurb, out);
            }
        }
    }
}

// Round 13
// 1066.887 us; speedup vs baseline: 1.0884x; 1.0884x over previous
//
#include <hip/hip_runtime.h>
#include <hip/hip_bf16.h>
#include <math.h>

#define N_NODES 50000
#define NOFF    50004   // padded off-array stride (16B-aligned int4 stores)
#define NBLK    49      // ceil(N_NODES/1024) scan blocks per type
#define F_IN    256
#define H       128
#define HEADS   4
#define HH      512   // HEADS*H
#define L_LAYERS 3
#define T_TYPES  3
#define E_EDGES  250000
#define NEG      0.2f

#define GEMM_RB  391          // row blocks: ceil(50000/128)
#define GEMM_GRID (GEMM_RB*8) // 3128, divisible by 8 XCDs

// combo_a block ranges: featconv | wconv | pconv | detect
#define CA_FEAT  12500        // 50000*256/4/256
#define CA_WCONV 4608         // 9*1024*128/256
#define CA_PCONV 128          // 128*256/256
#define CA_TOTAL (CA_FEAT + CA_WCONV + CA_PCONV + 1)
// combo_b: init_gemm | hist
#define CB_INIT  391
#define CB_HIST  2930         // ceil(750000/256)
#define CB_TOTAL (CB_INIT + CB_HIST)
// combo_c: ln_combine(256t) | scanA
#define CC_LN    3125         // 50000/16
#define CC_SCANA (T_TYPES*NBLK)
#define CC_TOTAL (CC_LN + CC_SCANA)

typedef __attribute__((ext_vector_type(8))) short short8_t;   // 8 bf16 (4 VGPRs)
typedef __attribute__((ext_vector_type(4))) float float4_t;
typedef __attribute__((ext_vector_type(2))) float float2_t;

__device__ __forceinline__ float leaky(float x) { return x > 0.f ? x : NEG * x; }

// hardware RNE f32->bf16 (v_cvt_pk_bf16_f32, 1 VALU op)
__device__ __forceinline__ unsigned int cvt_pk_bf16(float lo, float hi) {
    unsigned int d;
    asm("v_cvt_pk_bf16_f32 %0, %1, %2" : "=v"(d) : "v"(lo), "v"(hi));
    return d;
}

__device__ __forceinline__ unsigned short f2bf(float f) {
    return (unsigned short)cvt_pk_bf16(f, f);
}

__device__ __forceinline__ float bf2f(unsigned short u) {
    union { unsigned int i; float f; } v; v.i = ((unsigned)u) << 16; return v.f;
}

// ---- packed fp32 (VOP3P, full-rate on CDNA) ----
__device__ __forceinline__ float2_t pk_add(float2_t a, float2_t b) {
    float2_t d;
    asm("v_pk_add_f32 %0, %1, %2" : "=v"(d) : "v"(a), "v"(b));
    return d;
}
__device__ __forceinline__ float2_t pk_fma(float2_t a, float2_t b, float2_t c) {
    float2_t d;
    asm("v_pk_fma_f32 %0, %1, %2, %3" : "=v"(d) : "v"(a), "v"(b), "v"(c));
    return d;
}
__device__ __forceinline__ float2_t pk_abs(float2_t a) {
    union { float2_t f; unsigned int u[2]; } v; v.f = a;
    v.u[0] &= 0x7fffffffu;
    v.u[1] &= 0x7fffffffu;
    return v.f;
}

// single-instruction 2^x (avoids glibc __exp2f macro collision)
__device__ __forceinline__ float fast_exp2(float x) {
    return __builtin_amdgcn_exp2f(x);
}

// DPP butterfly step: x += dpp_perm(x). Full-rate VALU, no LDS pipe.
template <int CTRL>
__device__ __forceinline__ float dpp_add(float x) {
    union { float f; int i; } a, b;
    a.f = x;
    b.i = __builtin_amdgcn_update_dpp(0, a.i, CTRL, 0xf, 0xf, true);
    return x + b.f;
}
__device__ __forceinline__ float row16_reduce(float p) {
    p = dpp_add<0xB1>(p);    // quad_perm xor1
    p = dpp_add<0x4E>(p);    // quad_perm xor2
    p = dpp_add<0x141>(p);   // row_half_mirror (xor4)
    p = dpp_add<0x140>(p);   // row_mirror (xor8)
    return p;
}

// unpack uint4 (8 bf16) -> 4 packed float2
__device__ __forceinline__ void unpack_pk(uint4 q, float2_t* o) {
    union { unsigned int i; float f; } v;
    float2_t t;
    v.i = q.x << 16;         t.x = v.f;
    v.i = q.x & 0xffff0000u; t.y = v.f; o[0] = t;
    v.i = q.y << 16;         t.x = v.f;
    v.i = q.y & 0xffff0000u; t.y = v.f; o[1] = t;
    v.i = q.z << 16;         t.x = v.f;
    v.i = q.z & 0xffff0000u; t.y = v.f; o[2] = t;
    v.i = q.w << 16;         t.x = v.f;
    v.i = q.w & 0xffff0000u; t.y = v.f; o[3] = t;
}

// stage a 128x128 bf16 tile (16B chunks, XOR swizzle)
__device__ __forceinline__ void stage_tile(unsigned short* dst, const unsigned short* src,
                                           int rbase, int kbase, int tid, bool guardRows) {
    #pragma unroll
    for (int it = 0; it < 8; ++it) {
        int c = it * 256 + tid;          // 0..2047
        int r = c >> 4, k8 = c & 15;
        int slot = (k8 ^ (r & 15)) * 8;
        uint4 v = make_uint4(0, 0, 0, 0);
        int row = rbase + r;
        if (!guardRows || row < N_NODES)
            v = *(const uint4*)(src + (size_t)row * 256 + kbase + k8 * 8);
        *(uint4*)(dst + r * 128 + slot) = v;
    }
}

// ================= combo_a: featconv | wconv | pconv | detect =================
__global__ __launch_bounds__(256) void combo_a_kernel(
    const float* __restrict__ feat, unsigned short* __restrict__ fHi, unsigned short* __restrict__ fLo,
    const float* __restrict__ Wl, const float* __restrict__ Wr, unsigned short* __restrict__ Wt,
    const float* __restrict__ pw, unsigned short* __restrict__ pWtHi, unsigned short* __restrict__ pWtLo,
    const int* __restrict__ edst, int* __restrict__ flag)
{
    __shared__ int s_any;
    const int bid = blockIdx.x;
    const int tid = threadIdx.x;
    if (bid < CA_FEAT) {
        // featconv: feat fp32 -> split bf16 (exact cover: 12500*256*4 = 12.8M elems)
        size_t i = ((size_t)bid * 256 + tid) * 4;
        float4 v = *(const float4*)(feat + i);
        ushort4 h, l;
        h.x = f2bf(v.x); l.x = f2bf(v.x - bf2f(h.x));
        h.y = f2bf(v.y); l.y = f2bf(v.y - bf2f(h.y));
        h.z = f2bf(v.z); l.z = f2bf(v.z - bf2f(h.z));
        h.w = f2bf(v.w); l.w = f2bf(v.w - bf2f(h.w));
        *(ushort4*)(fHi + i) = h;
        *(ushort4*)(fLo + i) = l;
    } else if (bid < CA_FEAT + CA_WCONV) {
        // wconv: Wt[lt][c][k] = bf16(W{l,r}[lt][k][c])  (exact cover)
        int idx = (bid - CA_FEAT) * 256 + tid;
        int lt  = idx / (1024 * H);
        int rem = idx - lt * (1024 * H);
        int c   = rem / H;
        int k   = rem - c * H;
        float v = (c < HH) ? Wl[(size_t)lt * H * HH + (size_t)k * HH + c]
                           : Wr[(size_t)lt * H * HH + (size_t)k * HH + (c - HH)];
        Wt[idx] = f2bf(v);
    } else if (bid < CA_FEAT + CA_WCONV + CA_PCONV) {
        // pconv (exact cover: 128*256 = 32768)
        int idx = (bid - CA_FEAT - CA_WCONV) * 256 + tid;
        int c = idx / F_IN, k = idx - c * F_IN;
        float v = pw[(size_t)k * H + c];
        unsigned short hi = f2bf(v);
        pWtHi[idx] = hi;
        pWtLo[idx] = f2bf(v - bf2f(hi));
    } else {
        // detect: int64 vs int32 edge layout
        if (tid == 0) s_any = 0;
        __syncthreads();
        int a = 0;
        #pragma unroll
        for (int j = 0; j < 8; ++j) a |= edst[2 * (tid * 8 + j) + 1];
        if (a) atomicOr(&s_any, 1);
        __syncthreads();
        if (tid == 0) *flag = s_any ? 0 : 1;
    }
}

// init GEMM tile body (split-bf16 MFMA, 3 hi/lo passes, K=256)
__device__ __forceinline__ void init_gemm_body(
    unsigned short* smem,
    const unsigned short* __restrict__ fHi, const unsigned short* __restrict__ fLo,
    const unsigned short* __restrict__ pWtHi, const unsigned short* __restrict__ pWtLo,
    float* __restrict__ proj, int bid, int tid)
{
    unsigned short* As = smem;
    unsigned short* Bs = smem + 16384;
    const int nb = bid * 128;

    const int wv = tid >> 6, lane = tid & 63;
    const int lm = lane & 15, kg = lane >> 4;
    const int wm = (wv & 1) * 64, wn = (wv >> 1) * 64;
    float4_t acc[4][4];
    #pragma unroll
    for (int i = 0; i < 4; ++i)
        #pragma unroll
        for (int j = 0; j < 4; ++j)
            acc[i][j] = (float4_t){0.f, 0.f, 0.f, 0.f};

    auto compute = [&]() {
        #pragma unroll
        for (int ks = 0; ks < 4; ++ks) {
            const int K8 = ks * 4 + kg;
            const int slot = (K8 ^ lm) * 8;
            short8_t a[4], b[4];
            #pragma unroll
            for (int i = 0; i < 4; ++i) {
                a[i] = *(const short8_t*)(As + (wm + i * 16 + lm) * 128 + slot);
                b[i] = *(const short8_t*)(Bs + (wn + i * 16 + lm) * 128 + slot);
            }
            #pragma unroll
            for (int i = 0; i < 4; ++i)
                #pragma unroll
                for (int j = 0; j < 4; ++j)
                    acc[i][j] = __builtin_amdgcn_mfma_f32_16x16x32_bf16(a[i], b[j], acc[i][j], 0, 0, 0);
        }
    };

    #pragma unroll
    for (int kh = 0; kh < 2; ++kh) {
        const int kbase = kh * 128;
        stage_tile(As, fHi, nb, kbase, tid, true);
        stage_tile(Bs, pWtHi, 0, kbase, tid, false);
        __syncthreads();
        compute();
        __syncthreads();
        stage_tile(Bs, pWtLo, 0, kbase, tid, false);
        __syncthreads();
        compute();
        __syncthreads();
        stage_tile(As, fLo, nb, kbase, tid, true);
        stage_tile(Bs, pWtHi, 0, kbase, tid, false);
        __syncthreads();
        compute();
        __syncthreads();
    }

    #pragma unroll
    for (int i = 0; i < 4; ++i) {
        #pragma unroll
        for (int r = 0; r < 4; ++r) {
            int node = nb + wm + i * 16 + kg * 4 + r;
            if (node < N_NODES) {
                #pragma unroll
                for (int j = 0; j < 4; ++j)
                    proj[(size_t)node * H + wn + j * 16 + lm] = acc[i][j][r];
            }
        }
    }
}

// ================= combo_b: init_gemm | hist =================
__global__ __launch_bounds__(256) void combo_b_kernel(
    const unsigned short* __restrict__ fHi, const unsigned short* __restrict__ fLo,
    const unsigned short* __restrict__ pWtHi, const unsigned short* __restrict__ pWtLo,
    float* __restrict__ proj,
    const int* __restrict__ edst, int* __restrict__ counts, const int* __restrict__ flag)
{
    __shared__ unsigned short smem[32768];
    const int bid = blockIdx.x;
    const int tid = threadIdx.x;
    if (bid < CB_INIT) {
        init_gemm_body(smem, fHi, fLo, pWtHi, pWtLo, proj, bid, tid);
    } else {
        int idx = (bid - CB_INIT) * 256 + tid;
        if (idx < T_TYPES * E_EDGES) {
            int sh = *flag;
            int t = idx / E_EDGES;
            int d = edst[(size_t)idx << sh];
            if ((unsigned)d < N_NODES)
                atomicAdd(&counts[t * N_NODES + d], 1);
        }
    }
}

// ================= combo_c: ln_combine (256t, two independent halves) | scanA =================
__global__ __launch_bounds__(256) void combo_c_kernel(
    const float* __restrict__ proj, const float* __restrict__ emb,
    const float* __restrict__ pb, const float* __restrict__ g, const float* __restrict__ b,
    float* __restrict__ x0, unsigned short* __restrict__ xcurb,
    const int* __restrict__ counts, int* __restrict__ bsum)
{
    __shared__ float s0[4], s1[4];
    __shared__ int ws[4];
    const int bid = blockIdx.x;
    const int tid = threadIdx.x;
    if (bid < CC_LN) {
        // ln_combine: 16 nodes/block, halves h=0/1 handle 8 nodes each. 3125*16 = 50000 exact.
        const int h = tid >> 7;
        const int c = tid & 127;
        const int wv = tid >> 6;          // 0..3; half h owns waves {2h, 2h+1}
        const int nb = bid * 16 + h * 8;
        float acc[8];
        #pragma unroll
        for (int nn = 0; nn < 8; ++nn)
            acc[nn] = proj[(size_t)(nb + nn) * H + c];
        const float pbc = pb[c], gc = g[c], bc = b[c];
        for (int nn = 0; nn < 8; ++nn) {
            float v = acc[nn] + pbc;
            float sum = v, sq = v * v;
            for (int o = 32; o > 0; o >>= 1) { sum += __shfl_down(sum, o); sq += __shfl_down(sq, o); }
            if ((tid & 63) == 0) { s0[wv] = sum; s1[wv] = sq; }
            __syncthreads();
            float tot = s0[2 * h] + s0[2 * h + 1], tq = s1[2 * h] + s1[2 * h + 1];
            __syncthreads();
            float mu = tot * (1.f / H);
            float var = tq * (1.f / H) - mu * mu;
            acc[nn] = leaky((v - mu) * rsqrtf(var + 1e-5f) * gc + bc);
        }
        for (int nn = 0; nn < 8; ++nn) {
            int node = nb + nn;
            float ev = emb[(size_t)node * H + c];
            float sq = ev * ev;
            for (int o = 32; o > 0; o >>= 1) sq += __shfl_down(sq, o);
            if ((tid & 63) == 0) s0[wv] = sq;
            __syncthreads();
            float nrm = sqrtf(s0[2 * h] + s0[2 * h + 1]);
            __syncthreads();
            float nev = ev / fmaxf(nrm, 1e-12f);
            float xv = 0.7f * acc[nn] + 0.5f * nev;
            x0[(size_t)node * H + c] = xv;
            xcurb[(size_t)node * H + c] = f2bf(xv);
        }
    } else {
        // scanA: per-block partial sums of counts
        const int sb = bid - CC_LN;
        const int t = sb / NBLK, ch = sb % NBLK;
        const int lane = tid & 63;
        const int* cnt = counts + t * N_NODES;
        int i0 = ch * 1024 + tid * 4;
        int s = 0;
        if (i0 + 3 < N_NODES) { int4 v = *(const int4*)(cnt + i0); s = v.x + v.y + v.z + v.w; }
        else { for (int j = 0; j < 4; ++j) { int i = i0 + j; if (i < N_NODES) s += cnt[i]; } }
        #pragma unroll
        for (int o = 32; o > 0; o >>= 1) s += __shfl_xor(s, o);
        if (lane == 0) ws[tid >> 6] = s;
        __syncthreads();
        if (tid == 0) bsum[sb] = ws[0] + ws[1] + ws[2] + ws[3];
    }
}

// ================= scan_c2: scanC with scanB's chunk-prefix folded in =================
__global__ __launch_bounds__(256) void scan_c2_kernel(const int* counts,
                                                      const int* __restrict__ bsum,
                                                      int* __restrict__ off,
                                                      int* cursor) {
    const int b = blockIdx.x;
    const int t = b / NBLK, ch = b % NBLK;
    const int tid = threadIdx.x, lane = tid & 63, w = tid >> 6;
    __shared__ int ws[4];
    // exclusive prefix of raw chunk sums (<=48 adds, redundant per thread)
    int run = 0;
    for (int c = 0; c < ch; ++c) run += bsum[t * NBLK + c];
    const int* cnt = counts + t * N_NODES;
    int i0 = ch * 1024 + tid * 4;
    int v0 = 0, v1 = 0, v2 = 0, v3 = 0;
    if (i0 + 3 < N_NODES) { int4 v = *(const int4*)(cnt + i0); v0 = v.x; v1 = v.y; v2 = v.z; v3 = v.w; }
    else {
        if (i0     < N_NODES) v0 = cnt[i0];
        if (i0 + 1 < N_NODES) v1 = cnt[i0 + 1];
        if (i0 + 2 < N_NODES) v2 = cnt[i0 + 2];
        if (i0 + 3 < N_NODES) v3 = cnt[i0 + 3];
    }
    int s = v0 + v1 + v2 + v3;
    int x = s;
    #pragma unroll
    for (int o = 1; o < 64; o <<= 1) { int y = __shfl_up(x, o); if (lane >= o) x += y; }
    if (lane == 63) ws[w] = x;
    __syncthreads();
    int woff = 0;
    #pragma unroll
    for (int j = 0; j < 4; ++j) woff += (j < w) ? ws[j] : 0;
    int base = run + woff + (x - s);
    int e0 = base, e1 = e0 + v0, e2 = e1 + v1, e3 = e2 + v2;
    if (i0 + 3 < N_NODES) {
        *(int4*)(off + t * NOFF + i0)       = make_int4(e0, e1, e2, e3);
        *(int4*)(cursor + t * N_NODES + i0) = make_int4(e0, e1, e2, e3);
    } else {
        if (i0     < N_NODES) { off[t * NOFF + i0]     = e0; cursor[t * N_NODES + i0]     = e0; }
        if (i0 + 1 < N_NODES) { off[t * NOFF + i0 + 1] = e1; cursor[t * N_NODES + i0 + 1] = e1; }
        if (i0 + 2 < N_NODES) { off[t * NOFF + i0 + 2] = e2; cursor[t * N_NODES + i0 + 2] = e2; }
        if (i0 + 3 < N_NODES) { off[t * NOFF + i0 + 3] = e3; cursor[t * N_NODES + i0 + 3] = e3; }
    }
    // total for this type (scanB's second job): last chunk, last thread holds block total
    if (ch == NBLK - 1 && tid == 255)
        off[t * NOFF + N_NODES] = run + woff + x;
}

__global__ void scatter_kernel(const int* __restrict__ esrc, const int* __restrict__ edst,
                               int* __restrict__ cursor, int* __restrict__ csrc,
                               const int* __restrict__ flag) {
    int idx = blockIdx.x * 256 + threadIdx.x;
    if (idx < T_TYPES * E_EDGES) {
        int sh = *flag;
        int t = idx / E_EDGES;
        int d = edst[(size_t)idx << sh];
        if ((unsigned)d >= N_NODES) return;
        int s = esrc[(size_t)idx << sh];
        if ((unsigned)s >= N_NODES) s = 0;
        int pos = atomicAdd(&cursor[t * N_NODES + d], 1);
        if ((unsigned)pos < E_EDGES)
            csrc[(size_t)t * E_EDGES + pos] = s;
    }
}

// ---------------- MFMA GEMM: [N,128]bf16 @ Wt^T -> XL|XR bf16, XCD-chunked swizzle --------
__global__ __launch_bounds__(256) void gemm_mfma_kernel(
    const unsigned short* __restrict__ x,    // [N][128] bf16
    const unsigned short* __restrict__ Wt,   // [1024][128] bf16 (this layer-type)
    unsigned short* __restrict__ XL, unsigned short* __restrict__ XR)
{
    __shared__ unsigned short smem[32768];   // As 32K | Bs 32K, then C overlay
    unsigned short* As = smem;
    unsigned short* Bs = smem + 16384;
    const int tid = threadIdx.x;

    // bijective chunked XCD swizzle: 3128 % 8 == 0
    const int f    = blockIdx.x;
    const int g    = (f % 8) * GEMM_RB + (f / 8);
    const int rowb = g >> 3;
    const int colb = g & 7;
    const int nb = rowb * 128;
    const int cb = colb * 128;

    #pragma unroll
    for (int it = 0; it < 8; ++it) {
        int c = it * 256 + tid;
        int r = c >> 4;
        int k8 = c & 15;
        int slot = (k8 ^ (r & 15)) * 8;
        int node = nb + r;
        uint4 va = make_uint4(0, 0, 0, 0);
        if (node < N_NODES) va = *(const uint4*)(x + (size_t)node * H + k8 * 8);
        *(uint4*)(As + r * H + slot) = va;
        uint4 vb = *(const uint4*)(Wt + (size_t)(cb + r) * H + k8 * 8);
        *(uint4*)(Bs + r * H + slot) = vb;
    }
    __syncthreads();

    const int wv = tid >> 6, lane = tid & 63;
    const int lm = lane & 15, kg = lane >> 4;
    const int wm = (wv & 1) * 64, wn = (wv >> 1) * 64;
    float4_t acc[4][4];
    #pragma unroll
    for (int i = 0; i < 4; ++i)
        #pragma unroll
        for (int j = 0; j < 4; ++j)
            acc[i][j] = (float4_t){0.f, 0.f, 0.f, 0.f};

    #pragma unroll
    for (int ks = 0; ks < 4; ++ks) {
        const int K8 = ks * 4 + kg;
        const int slot = (K8 ^ lm) * 8;
        short8_t a[4], b[4];
        #pragma unroll
        for (int i = 0; i < 4; ++i) {
            a[i] = *(const short8_t*)(As + (wm + i * 16 + lm) * H + slot);
            b[i] = *(const short8_t*)(Bs + (wn + i * 16 + lm) * H + slot);
        }
        #pragma unroll
        for (int i = 0; i < 4; ++i)
            #pragma unroll
            for (int j = 0; j < 4; ++j)
                acc[i][j] = __builtin_amdgcn_mfma_f32_16x16x32_bf16(a[i], b[j], acc[i][j], 0, 0, 0);
    }
    __syncthreads();

    unsigned short* Cs = smem;
    #pragma unroll
    for (int i = 0; i < 4; ++i) {
        int row0 = wm + i * 16 + kg * 4;
        #pragma unroll
        for (int j = 0; j < 4; ++j) {
            int col = wn + j * 16 + lm;
            #pragma unroll
            for (int r = 0; r < 4; ++r)
                Cs[(row0 + r) * 136 + col] = f2bf(acc[i][j][r]);
        }
    }
    __syncthreads();

    unsigned short* O = (colb < 4) ? XL : XR;
    const int cbase = (colb < 4) ? cb : cb - HH;
    #pragma unroll
    for (int it = 0; it < 8; ++it) {
        int c = it * 256 + tid;
        int r = c >> 4, k8 = (c & 15) * 8;
        int node = nb + r;
        if (node < N_NODES)
            *(uint4*)(O + (size_t)node * HH + cbase + k8) = *(const uint4*)(Cs + r * 136 + k8);
    }
}

// ---------------- per-dst flash-style GATv2 aggregation: 1 wave = 1 dst node (R9 proven) ---
__global__ __launch_bounds__(64) void aggregate_kernel(
    const unsigned short* __restrict__ XL, const unsigned short* __restrict__ XR,
    const float* __restrict__ att_t, const float* __restrict__ bias_t,
    const int* __restrict__ off, const int* __restrict__ csrc,
    float* __restrict__ xacc, int first,
    int fin, const float* __restrict__ x0, const float* __restrict__ skipw,
    int li, int last, unsigned short* __restrict__ xcurb, float* __restrict__ out)
{
    const int lane = threadIdx.x;
    const int d = blockIdx.x;
    if (d >= N_NODES) return;
    const int jb = lane * 8;
    const float L2E = 1.4426950408889634f;

    float2_t rv[4], c1[4], c2[4], acc2[4];
    {
        uint4 q = *(const uint4*)(XR + (size_t)d * HH + jb);
        unpack_pk(q, rv);
        float4 u0 = *(const float4*)(att_t + jb);
        float4 u1 = *(const float4*)(att_t + jb + 4);
        float av[8] = {u0.x, u0.y, u0.z, u0.w, u1.x, u1.y, u1.z, u1.w};
        #pragma unroll
        for (int u = 0; u < 4; ++u) {
            c1[u] = (float2_t){0.6f * L2E * av[2 * u], 0.6f * L2E * av[2 * u + 1]};
            c2[u] = (float2_t){0.4f * L2E * av[2 * u], 0.4f * L2E * av[2 * u + 1]};
            acc2[u] = (float2_t){0.f, 0.f};
        }
    }
    float den = 0.f;

    const int e0 = off[d];
    const int cnt = off[d + 1] - e0;

    uint4 q0 = make_uint4(0, 0, 0, 0), q1 = q0;
    unsigned s2 = 0, s3 = 0;
    if (cnt > 0) q0 = *(const uint4*)(XL + (size_t)((unsigned)csrc[e0])     * HH + jb);
    if (cnt > 1) q1 = *(const uint4*)(XL + (size_t)((unsigned)csrc[e0 + 1]) * HH + jb);
    if (cnt > 2) s2 = (unsigned)csrc[e0 + 2];
    if (cnt > 3) s3 = (unsigned)csrc[e0 + 3];

    int e = 0;
    for (; e + 1 < cnt; e += 2) {
        float2_t lv0[4], lv1[4];
        unpack_pk(q0, lv0);
        unpack_pk(q1, lv1);
        if (e + 2 < cnt) q0 = *(const uint4*)(XL + (size_t)s2 * HH + jb);
        if (e + 3 < cnt) q1 = *(const uint4*)(XL + (size_t)s3 * HH + jb);
        if (e + 4 < cnt) s2 = (unsigned)csrc[e0 + e + 4];
        if (e + 5 < cnt) s3 = (unsigned)csrc[e0 + e + 5];

        float2_t p20 = (float2_t){0.f, 0.f};
        float2_t p21 = (float2_t){0.f, 0.f};
        #pragma unroll
        for (int u = 0; u < 4; ++u) {
            float2_t m0 = pk_add(lv0[u], rv[u]);
            float2_t m1 = pk_add(lv1[u], rv[u]);
            float2_t a0 = pk_abs(m0);
            float2_t a1 = pk_abs(m1);
            p20 = pk_fma(c1[u], m0, p20);
            p21 = pk_fma(c1[u], m1, p21);
            p20 = pk_fma(c2[u], a0, p20);
            p21 = pk_fma(c2[u], a1, p21);
        }
        float p0 = row16_reduce(p20.x + p20.y);
        float p1 = row16_reduce(p21.x + p21.y);
        float w0 = fast_exp2(p0);
        float w1 = fast_exp2(p1);
        den += w0 + w1;
        float2_t w20 = (float2_t){w0, w0};
        float2_t w21 = (float2_t){w1, w1};
        #pragma unroll
        for (int u = 0; u < 4; ++u) {
            acc2[u] = pk_fma(w20, lv0[u], acc2[u]);
            acc2[u] = pk_fma(w21, lv1[u], acc2[u]);
        }
    }
    if (e < cnt) {
        float2_t lv0[4];
        unpack_pk(q0, lv0);
        float2_t p20 = (float2_t){0.f, 0.f};
        #pragma unroll
        for (int u = 0; u < 4; ++u) {
            float2_t m0 = pk_add(lv0[u], rv[u]);
            float2_t a0 = pk_abs(m0);
            p20 = pk_fma(c1[u], m0, p20);
            p20 = pk_fma(c2[u], a0, p20);
        }
        float p0 = row16_reduce(p20.x + p20.y);
        float w0 = fast_exp2(p0);
        den += w0;
        float2_t w20 = (float2_t){w0, w0};
        #pragma unroll
        for (int u = 0; u < 4; ++u) acc2[u] = pk_fma(w20, lv0[u], acc2[u]);
    }

    float inv = 1.f / (den + 1e-16f);
    float o[8];
    #pragma unroll
    for (int u = 0; u < 4; ++u) { o[2 * u] = acc2[u].x; o[2 * u + 1] = acc2[u].y; }
    #pragma unroll
    for (int u = 0; u < 8; ++u) {
        float v = o[u] * inv;
        v += __shfl_xor(v, 16);
        v += __shfl_xor(v, 32);
        o[u] = v * 0.25f;
    }
    if (lane < 16) {
        float* dst = xacc + (size_t)d * H + jb;
        #pragma unroll
        for (int u = 0; u < 8; ++u) o[u] += bias_t[jb + u];
        if (!fin) {
            float4 o0 = make_float4(o[0], o[1], o[2], o[3]);
            float4 o1 = make_float4(o[4], o[5], o[6], o[7]);
            if (first) {
                *(float4*)dst = o0;
                *(float4*)(dst + 4) = o1;
            } else {
                float4 c0 = *(const float4*)dst, c1v = *(const float4*)(dst + 4);
                o0.x += c0.x; o0.y += c0.y; o0.z += c0.z; o0.w += c0.w;
                o1.x += c1v.x; o1.y += c1v.y; o1.z += c1v.z; o1.w += c1v.w;
                *(float4*)dst = o0;
                *(float4*)(dst + 4) = o1;
            }
        } else {
            float sw = 1.f / (1.f + __expf(-skipw[li]));
            float4 c0 = *(const float4*)dst, c1v = *(const float4*)(dst + 4);
            float a0 = c0.x + o[0], a1 = c0.y + o[1], a2 = c0.z + o[2], a3 = c0.w + o[3];
            float a4 = c1v.x + o[4], a5 = c1v.y + o[5], a6 = c1v.z + o[6], a7 = c1v.w + o[7];
            const float* z = x0 + (size_t)d * H + jb;
            float4 z0 = *(const float4*)z, z1 = *(const float4*)(z + 4);
            float r0 = leaky(a0 * (1.f / 3.f)) + sw * z0.x;
            float r1 = leaky(a1 * (1.f / 3.f)) + sw * z0.y;
            float r2 = leaky(a2 * (1.f / 3.f)) + sw * z0.z;
            float r3 = leaky(a3 * (1.f / 3.f)) + sw * z0.w;
            float r4 = leaky(a4 * (1.f / 3.f)) + sw * z1.x;
            float r5 = leaky(a5 * (1.f / 3.f)) + sw * z1.y;
            float r6 = leaky(a6 * (1.f / 3.f)) + sw * z1.z;
            float r7 = leaky(a7 * (1.f / 3.f)) + sw * z1.w;
            if (last) {
                float* op = out + (size_t)d * H + jb;
                *(float4*)op       = make_float4(r0, r1, r2, r3);
                *(float4*)(op + 4) = make_float4(r4, r5, r6, r7);
            } else {
                unsigned int w0 = cvt_pk_bf16(r0, r1);
                unsigned int w1 = cvt_pk_bf16(r2, r3);
                unsigned int w2 = cvt_pk_bf16(r4, r5);
                unsigned int w3 = cvt_pk_bf16(r6, r7);
                *(uint4*)(xcurb + (size_t)d * H + jb) = make_uint4(w0, w1, w2, w3);
            }
        }
    }
}

extern "C" void kernel_launch(void* const* d_in, const int* in_sizes, int n_in,
                              void* d_out, int out_size, void* d_ws, size_t ws_size,
                              hipStream_t stream)
{
    const float* feat   = (const float*)d_in[0];
    const float* emb    = (const float*)d_in[1];
    const float* proj_w = (const float*)d_in[2];
    const float* proj_b = (const float*)d_in[3];
    const float* ln_g   = (const float*)d_in[4];
    const float* ln_b   = (const float*)d_in[5];
    const float* skip_w = (const float*)d_in[6];
    const float* Wl     = (const float*)d_in[7];
    const float* Wr     = (const float*)d_in[8];
    const float* att    = (const float*)d_in[9];
    const float* bias   = (const float*)d_in[10];
    const int*   esrc   = (const int*)d_in[11];
    const int*   edst   = (const int*)d_in[12];
    float* out = (float*)d_out;

    char* p = (char*)d_ws;
    auto alloc = [&](size_t bytes) -> char* {
        char* r = p; p += (bytes + 255) & ~(size_t)255; return r;
    };
    float* x0             = (float*)alloc((size_t)N_NODES * H * 4);
    unsigned short* xcurb = (unsigned short*)alloc((size_t)N_NODES * H * 2);
    unsigned short* XL    = (unsigned short*)alloc((size_t)N_NODES * HH * 2);
    unsigned short* XR    = (unsigned short*)alloc((size_t)N_NODES * HH * 2);
    unsigned short* Wt    = (unsigned short*)alloc((size_t)L_LAYERS * T_TYPES * 1024 * H * 2);
    unsigned short* pWtHi = (unsigned short*)alloc((size_t)H * F_IN * 2);
    unsigned short* pWtLo = (unsigned short*)alloc((size_t)H * F_IN * 2);
    int* off    = (int*)alloc((size_t)T_TYPES * NOFF * 4);
    int* cursor = (int*)alloc((size_t)T_TYPES * N_NODES * 4);
    int* csrc   = (int*)alloc((size_t)T_TYPES * E_EDGES * 4);
    int* bsum   = (int*)alloc((size_t)T_TYPES * NBLK * 4);
    int* eflag  = (int*)alloc(256);
    float* xacc = out;  // scratch accumulator aliases d_out

    // init-phase scratch aliases the (still-dead) XL/XR regions
    float* proj          = (float*)XL;                                   // 25.6 MB <= 51.2
    unsigned short* fHi  = XR;                                           // 25.6 MB
    unsigned short* fLo  = XR + (size_t)N_NODES * F_IN;                  // 25.6 MB

    hipMemsetAsync(cursor, 0, (size_t)T_TYPES * N_NODES * 4, stream);

    // prologue: 5 dispatches (was 11) — independent chains co-dispatched via blockIdx ranges
    combo_a_kernel<<<CA_TOTAL, 256, 0, stream>>>(feat, fHi, fLo, Wl, Wr, Wt,
                                                 proj_w, pWtHi, pWtLo, edst, eflag);
    combo_b_kernel<<<CB_TOTAL, 256, 0, stream>>>(fHi, fLo, pWtHi, pWtLo, proj,
                                                 edst, cursor, eflag);
    combo_c_kernel<<<CC_TOTAL, 256, 0, stream>>>(proj, emb, proj_b, ln_g, ln_b,
                                                 x0, xcurb, cursor, bsum);
    scan_c2_kernel<<<T_TYPES * NBLK, 256, 0, stream>>>(cursor, bsum, off, cursor);
    scatter_kernel<<<(T_TYPES * E_EDGES + 255) / 256, 256, 0, stream>>>(esrc, edst, cursor, csrc, eflag);

    for (int i = 0; i < L_LAYERS; ++i) {
        for (int t = 0; t < T_TYPES; ++t) {
            const int lt = i * T_TYPES + t;
            const unsigned short* wt = Wt + (size_t)lt * 1024 * H;
            const float* at = att + (size_t)lt * HEADS * H;
            const float* bi = bias + (size_t)lt * H;
            gemm_mfma_kernel<<<GEMM_GRID, 256, 0, stream>>>(xcurb, wt, XL, XR);
            aggregate_kernel<<<N_NODES, 64, 0, stream>>>(
                XL, XR, at, bi, off + t * NOFF, csrc + (size_t)t * E_EDGES,
                xacc, (t == 0) ? 1 : 0,
                (t == T_TYPES - 1) ? 1 : 0, x0, skip_w, i,
                (i == L_LAYERS - 1) ? 1 : 0, xcurb, out);
        }
    }
}

// Round 14
// 979.237 us; speedup vs baseline: 1.1858x; 1.0895x over previous
//
#include <hip/hip_runtime.h>
#include <hip/hip_bf16.h>
#include <math.h>

#define N_NODES 50000
#define NOFF    50004   // padded off-array stride (16B-aligned int4 stores)
#define NBLK    49      // ceil(N_NODES/1024) scan blocks per type
#define F_IN    256
#define H       128
#define HEADS   4
#define HH      512   // HEADS*H
#define L_LAYERS 3
#define T_TYPES  3
#define E_EDGES  250000
#define NEG      0.2f

#define GEMM_RB  391          // row blocks: ceil(50000/128)
#define GEMM_GRID (GEMM_RB*8) // 3128, divisible by 8 XCDs

// combo_a block ranges: featconv | wconv | pconv | detect
#define CA_FEAT  12500        // 50000*256/4/256
#define CA_WCONV 4608         // 9*1024*128/256
#define CA_PCONV 128          // 128*256/256
#define CA_TOTAL (CA_FEAT + CA_WCONV + CA_PCONV + 1)
// combo_b: init_gemm | hist
#define CB_INIT  391
#define CB_HIST  2930         // ceil(750000/256)
#define CB_TOTAL (CB_INIT + CB_HIST)
// combo_c: ln_combine(256t) | scanA
#define CC_LN    3125         // 50000/16
#define CC_SCANA (T_TYPES*NBLK)
#define CC_TOTAL (CC_LN + CC_SCANA)

typedef __attribute__((ext_vector_type(8))) short short8_t;   // 8 bf16 (4 VGPRs)
typedef __attribute__((ext_vector_type(4))) float float4_t;
typedef __attribute__((ext_vector_type(2))) float float2_t;

__device__ __forceinline__ float leaky(float x) { return x > 0.f ? x : NEG * x; }

// hardware RNE f32->bf16 (v_cvt_pk_bf16_f32, 1 VALU op)
__device__ __forceinline__ unsigned int cvt_pk_bf16(float lo, float hi) {
    unsigned int d;
    asm("v_cvt_pk_bf16_f32 %0, %1, %2" : "=v"(d) : "v"(lo), "v"(hi));
    return d;
}

__device__ __forceinline__ unsigned short f2bf(float f) {
    return (unsigned short)cvt_pk_bf16(f, f);
}

__device__ __forceinline__ float bf2f(unsigned short u) {
    union { unsigned int i; float f; } v; v.i = ((unsigned)u) << 16; return v.f;
}

// ---- packed fp32 (VOP3P, full-rate on CDNA) ----
__device__ __forceinline__ float2_t pk_add(float2_t a, float2_t b) {
    float2_t d;
    asm("v_pk_add_f32 %0, %1, %2" : "=v"(d) : "v"(a), "v"(b));
    return d;
}
__device__ __forceinline__ float2_t pk_fma(float2_t a, float2_t b, float2_t c) {
    float2_t d;
    asm("v_pk_fma_f32 %0, %1, %2, %3" : "=v"(d) : "v"(a), "v"(b), "v"(c));
    return d;
}
__device__ __forceinline__ float2_t pk_abs(float2_t a) {
    union { float2_t f; unsigned int u[2]; } v; v.f = a;
    v.u[0] &= 0x7fffffffu;
    v.u[1] &= 0x7fffffffu;
    return v.f;
}

// single-instruction 2^x (avoids glibc __exp2f macro collision)
__device__ __forceinline__ float fast_exp2(float x) {
    return __builtin_amdgcn_exp2f(x);
}

// async global->LDS, 16B per lane; LDS dest is wave-uniform base + lane*16 (linear)
__device__ __forceinline__ void gload_lds16(const unsigned short* g, unsigned short* l) {
    __builtin_amdgcn_global_load_lds((const void*)g, (void*)l, 16, 0, 0);
}

// DPP butterfly step: x += dpp_perm(x). Full-rate VALU, no LDS pipe.
template <int CTRL>
__device__ __forceinline__ float dpp_add(float x) {
    union { float f; int i; } a, b;
    a.f = x;
    b.i = __builtin_amdgcn_update_dpp(0, a.i, CTRL, 0xf, 0xf, true);
    return x + b.f;
}
__device__ __forceinline__ float row16_reduce(float p) {
    p = dpp_add<0xB1>(p);    // quad_perm xor1
    p = dpp_add<0x4E>(p);    // quad_perm xor2
    p = dpp_add<0x141>(p);   // row_half_mirror (xor4)
    p = dpp_add<0x140>(p);   // row_mirror (xor8)
    return p;
}

// unpack uint4 (8 bf16) -> 4 packed float2
__device__ __forceinline__ void unpack_pk(uint4 q, float2_t* o) {
    union { unsigned int i; float f; } v;
    float2_t t;
    v.i = q.x << 16;         t.x = v.f;
    v.i = q.x & 0xffff0000u; t.y = v.f; o[0] = t;
    v.i = q.y << 16;         t.x = v.f;
    v.i = q.y & 0xffff0000u; t.y = v.f; o[1] = t;
    v.i = q.z << 16;         t.x = v.f;
    v.i = q.z & 0xffff0000u; t.y = v.f; o[2] = t;
    v.i = q.w << 16;         t.x = v.f;
    v.i = q.w & 0xffff0000u; t.y = v.f; o[3] = t;
}

// stage a 128x128 bf16 tile (16B chunks, XOR swizzle) -- reg-staged (init path only)
__device__ __forceinline__ void stage_tile(unsigned short* dst, const unsigned short* src,
                                           int rbase, int kbase, int tid, bool guardRows) {
    #pragma unroll
    for (int it = 0; it < 8; ++it) {
        int c = it * 256 + tid;          // 0..2047
        int r = c >> 4, k8 = c & 15;
        int slot = (k8 ^ (r & 15)) * 8;
        uint4 v = make_uint4(0, 0, 0, 0);
        int row = rbase + r;
        if (!guardRows || row < N_NODES)
            v = *(const uint4*)(src + (size_t)row * 256 + kbase + k8 * 8);
        *(uint4*)(dst + r * 128 + slot) = v;
    }
}

// ================= combo_a: featconv | wconv | pconv | detect =================
__global__ __launch_bounds__(256) void combo_a_kernel(
    const float* __restrict__ feat, unsigned short* __restrict__ fHi, unsigned short* __restrict__ fLo,
    const float* __restrict__ Wl, const float* __restrict__ Wr, unsigned short* __restrict__ Wt,
    const float* __restrict__ pw, unsigned short* __restrict__ pWtHi, unsigned short* __restrict__ pWtLo,
    const int* __restrict__ edst, int* __restrict__ flag)
{
    __shared__ int s_any;
    const int bid = blockIdx.x;
    const int tid = threadIdx.x;
    if (bid < CA_FEAT) {
        // featconv: feat fp32 -> split bf16 (exact cover: 12500*256*4 = 12.8M elems)
        size_t i = ((size_t)bid * 256 + tid) * 4;
        float4 v = *(const float4*)(feat + i);
        ushort4 h, l;
        h.x = f2bf(v.x); l.x = f2bf(v.x - bf2f(h.x));
        h.y = f2bf(v.y); l.y = f2bf(v.y - bf2f(h.y));
        h.z = f2bf(v.z); l.z = f2bf(v.z - bf2f(h.z));
        h.w = f2bf(v.w); l.w = f2bf(v.w - bf2f(h.w));
        *(ushort4*)(fHi + i) = h;
        *(ushort4*)(fLo + i) = l;
    } else if (bid < CA_FEAT + CA_WCONV) {
        // wconv: Wt[lt][c][k] = bf16(W{l,r}[lt][k][c])  (exact cover)
        int idx = (bid - CA_FEAT) * 256 + tid;
        int lt  = idx / (1024 * H);
        int rem = idx - lt * (1024 * H);
        int c   = rem / H;
        int k   = rem - c * H;
        float v = (c < HH) ? Wl[(size_t)lt * H * HH + (size_t)k * HH + c]
                           : Wr[(size_t)lt * H * HH + (size_t)k * HH + (c - HH)];
        Wt[idx] = f2bf(v);
    } else if (bid < CA_FEAT + CA_WCONV + CA_PCONV) {
        // pconv (exact cover: 128*256 = 32768)
        int idx = (bid - CA_FEAT - CA_WCONV) * 256 + tid;
        int c = idx / F_IN, k = idx - c * F_IN;
        float v = pw[(size_t)k * H + c];
        unsigned short hi = f2bf(v);
        pWtHi[idx] = hi;
        pWtLo[idx] = f2bf(v - bf2f(hi));
    } else {
        // detect: int64 vs int32 edge layout
        if (tid == 0) s_any = 0;
        __syncthreads();
        int a = 0;
        #pragma unroll
        for (int j = 0; j < 8; ++j) a |= edst[2 * (tid * 8 + j) + 1];
        if (a) atomicOr(&s_any, 1);
        __syncthreads();
        if (tid == 0) *flag = s_any ? 0 : 1;
    }
}

// init GEMM tile body (split-bf16 MFMA, 3 hi/lo passes, K=256)
__device__ __forceinline__ void init_gemm_body(
    unsigned short* smem,
    const unsigned short* __restrict__ fHi, const unsigned short* __restrict__ fLo,
    const unsigned short* __restrict__ pWtHi, const unsigned short* __restrict__ pWtLo,
    float* __restrict__ proj, int bid, int tid)
{
    unsigned short* As = smem;
    unsigned short* Bs = smem + 16384;
    const int nb = bid * 128;

    const int wv = tid >> 6, lane = tid & 63;
    const int lm = lane & 15, kg = lane >> 4;
    const int wm = (wv & 1) * 64, wn = (wv >> 1) * 64;
    float4_t acc[4][4];
    #pragma unroll
    for (int i = 0; i < 4; ++i)
        #pragma unroll
        for (int j = 0; j < 4; ++j)
            acc[i][j] = (float4_t){0.f, 0.f, 0.f, 0.f};

    auto compute = [&]() {
        #pragma unroll
        for (int ks = 0; ks < 4; ++ks) {
            const int K8 = ks * 4 + kg;
            const int slot = (K8 ^ lm) * 8;
            short8_t a[4], b[4];
            #pragma unroll
            for (int i = 0; i < 4; ++i) {
                a[i] = *(const short8_t*)(As + (wm + i * 16 + lm) * 128 + slot);
                b[i] = *(const short8_t*)(Bs + (wn + i * 16 + lm) * 128 + slot);
            }
            #pragma unroll
            for (int i = 0; i < 4; ++i)
                #pragma unroll
                for (int j = 0; j < 4; ++j)
                    acc[i][j] = __builtin_amdgcn_mfma_f32_16x16x32_bf16(a[i], b[j], acc[i][j], 0, 0, 0);
        }
    };

    #pragma unroll
    for (int kh = 0; kh < 2; ++kh) {
        const int kbase = kh * 128;
        stage_tile(As, fHi, nb, kbase, tid, true);
        stage_tile(Bs, pWtHi, 0, kbase, tid, false);
        __syncthreads();
        compute();
        __syncthreads();
        stage_tile(Bs, pWtLo, 0, kbase, tid, false);
        __syncthreads();
        compute();
        __syncthreads();
        stage_tile(As, fLo, nb, kbase, tid, true);
        stage_tile(Bs, pWtHi, 0, kbase, tid, false);
        __syncthreads();
        compute();
        __syncthreads();
    }

    #pragma unroll
    for (int i = 0; i < 4; ++i) {
        #pragma unroll
        for (int r = 0; r < 4; ++r) {
            int node = nb + wm + i * 16 + kg * 4 + r;
            if (node < N_NODES) {
                #pragma unroll
                for (int j = 0; j < 4; ++j)
                    proj[(size_t)node * H + wn + j * 16 + lm] = acc[i][j][r];
            }
        }
    }
}

// ================= combo_b: init_gemm | hist =================
__global__ __launch_bounds__(256) void combo_b_kernel(
    const unsigned short* __restrict__ fHi, const unsigned short* __restrict__ fLo,
    const unsigned short* __restrict__ pWtHi, const unsigned short* __restrict__ pWtLo,
    float* __restrict__ proj,
    const int* __restrict__ edst, int* __restrict__ counts, const int* __restrict__ flag)
{
    __shared__ unsigned short smem[32768];
    const int bid = blockIdx.x;
    const int tid = threadIdx.x;
    if (bid < CB_INIT) {
        init_gemm_body(smem, fHi, fLo, pWtHi, pWtLo, proj, bid, tid);
    } else {
        int idx = (bid - CB_INIT) * 256 + tid;
        if (idx < T_TYPES * E_EDGES) {
            int sh = *flag;
            int t = idx / E_EDGES;
            int d = edst[(size_t)idx << sh];
            if ((unsigned)d < N_NODES)
                atomicAdd(&counts[t * N_NODES + d], 1);
        }
    }
}

// ================= combo_c: ln_combine (256t, two independent halves) | scanA =================
__global__ __launch_bounds__(256) void combo_c_kernel(
    const float* __restrict__ proj, const float* __restrict__ emb,
    const float* __restrict__ pb, const float* __restrict__ g, const float* __restrict__ b,
    float* __restrict__ x0, unsigned short* __restrict__ xcurb,
    const int* __restrict__ counts, int* __restrict__ bsum)
{
    __shared__ float s0[4], s1[4];
    __shared__ int ws[4];
    const int bid = blockIdx.x;
    const int tid = threadIdx.x;
    if (bid < CC_LN) {
        // ln_combine: 16 nodes/block, halves h=0/1 handle 8 nodes each. 3125*16 = 50000 exact.
        const int h = tid >> 7;
        const int c = tid & 127;
        const int wv = tid >> 6;          // 0..3; half h owns waves {2h, 2h+1}
        const int nb = bid * 16 + h * 8;
        float acc[8];
        #pragma unroll
        for (int nn = 0; nn < 8; ++nn)
            acc[nn] = proj[(size_t)(nb + nn) * H + c];
        const float pbc = pb[c], gc = g[c], bc = b[c];
        for (int nn = 0; nn < 8; ++nn) {
            float v = acc[nn] + pbc;
            float sum = v, sq = v * v;
            for (int o = 32; o > 0; o >>= 1) { sum += __shfl_down(sum, o); sq += __shfl_down(sq, o); }
            if ((tid & 63) == 0) { s0[wv] = sum; s1[wv] = sq; }
            __syncthreads();
            float tot = s0[2 * h] + s0[2 * h + 1], tq = s1[2 * h] + s1[2 * h + 1];
            __syncthreads();
            float mu = tot * (1.f / H);
            float var = tq * (1.f / H) - mu * mu;
            acc[nn] = leaky((v - mu) * rsqrtf(var + 1e-5f) * gc + bc);
        }
        for (int nn = 0; nn < 8; ++nn) {
            int node = nb + nn;
            float ev = emb[(size_t)node * H + c];
            float sq = ev * ev;
            for (int o = 32; o > 0; o >>= 1) sq += __shfl_down(sq, o);
            if ((tid & 63) == 0) s0[wv] = sq;
            __syncthreads();
            float nrm = sqrtf(s0[2 * h] + s0[2 * h + 1]);
            __syncthreads();
            float nev = ev / fmaxf(nrm, 1e-12f);
            float xv = 0.7f * acc[nn] + 0.5f * nev;
            x0[(size_t)node * H + c] = xv;
            xcurb[(size_t)node * H + c] = f2bf(xv);
        }
    } else {
        // scanA: per-block partial sums of counts
        const int sb = bid - CC_LN;
        const int t = sb / NBLK, ch = sb % NBLK;
        const int lane = tid & 63;
        const int* cnt = counts + t * N_NODES;
        int i0 = ch * 1024 + tid * 4;
        int s = 0;
        if (i0 + 3 < N_NODES) { int4 v = *(const int4*)(cnt + i0); s = v.x + v.y + v.z + v.w; }
        else { for (int j = 0; j < 4; ++j) { int i = i0 + j; if (i < N_NODES) s += cnt[i]; } }
        #pragma unroll
        for (int o = 32; o > 0; o >>= 1) s += __shfl_xor(s, o);
        if (lane == 0) ws[tid >> 6] = s;
        __syncthreads();
        if (tid == 0) bsum[sb] = ws[0] + ws[1] + ws[2] + ws[3];
    }
}

// ================= scan_c2: scanC with scanB's chunk-prefix folded in =================
__global__ __launch_bounds__(256) void scan_c2_kernel(const int* counts,
                                                      const int* __restrict__ bsum,
                                                      int* __restrict__ off,
                                                      int* cursor) {
    const int b = blockIdx.x;
    const int t = b / NBLK, ch = b % NBLK;
    const int tid = threadIdx.x, lane = tid & 63, w = tid >> 6;
    __shared__ int ws[4];
    // exclusive prefix of raw chunk sums (<=48 adds, redundant per thread)
    int run = 0;
    for (int c = 0; c < ch; ++c) run += bsum[t * NBLK + c];
    const int* cnt = counts + t * N_NODES;
    int i0 = ch * 1024 + tid * 4;
    int v0 = 0, v1 = 0, v2 = 0, v3 = 0;
    if (i0 + 3 < N_NODES) { int4 v = *(const int4*)(cnt + i0); v0 = v.x; v1 = v.y; v2 = v.z; v3 = v.w; }
    else {
        if (i0     < N_NODES) v0 = cnt[i0];
        if (i0 + 1 < N_NODES) v1 = cnt[i0 + 1];
        if (i0 + 2 < N_NODES) v2 = cnt[i0 + 2];
        if (i0 + 3 < N_NODES) v3 = cnt[i0 + 3];
    }
    int s = v0 + v1 + v2 + v3;
    int x = s;
    #pragma unroll
    for (int o = 1; o < 64; o <<= 1) { int y = __shfl_up(x, o); if (lane >= o) x += y; }
    if (lane == 63) ws[w] = x;
    __syncthreads();
    int woff = 0;
    #pragma unroll
    for (int j = 0; j < 4; ++j) woff += (j < w) ? ws[j] : 0;
    int base = run + woff + (x - s);
    int e0 = base, e1 = e0 + v0, e2 = e1 + v1, e3 = e2 + v2;
    if (i0 + 3 < N_NODES) {
        *(int4*)(off + t * NOFF + i0)       = make_int4(e0, e1, e2, e3);
        *(int4*)(cursor + t * N_NODES + i0) = make_int4(e0, e1, e2, e3);
    } else {
        if (i0     < N_NODES) { off[t * NOFF + i0]     = e0; cursor[t * N_NODES + i0]     = e0; }
        if (i0 + 1 < N_NODES) { off[t * NOFF + i0 + 1] = e1; cursor[t * N_NODES + i0 + 1] = e1; }
        if (i0 + 2 < N_NODES) { off[t * NOFF + i0 + 2] = e2; cursor[t * N_NODES + i0 + 2] = e2; }
        if (i0 + 3 < N_NODES) { off[t * NOFF + i0 + 3] = e3; cursor[t * N_NODES + i0 + 3] = e3; }
    }
    // total for this type (scanB's second job): last chunk, last thread holds block total
    if (ch == NBLK - 1 && tid == 255)
        off[t * NOFF + N_NODES] = run + woff + x;
}

__global__ void scatter_kernel(const int* __restrict__ esrc, const int* __restrict__ edst,
                               int* __restrict__ cursor, int* __restrict__ csrc,
                               const int* __restrict__ flag) {
    int idx = blockIdx.x * 256 + threadIdx.x;
    if (idx < T_TYPES * E_EDGES) {
        int sh = *flag;
        int t = idx / E_EDGES;
        int d = edst[(size_t)idx << sh];
        if ((unsigned)d >= N_NODES) return;
        int s = esrc[(size_t)idx << sh];
        if ((unsigned)s >= N_NODES) s = 0;
        int pos = atomicAdd(&cursor[t * N_NODES + d], 1);
        if ((unsigned)pos < E_EDGES)
            csrc[(size_t)t * E_EDGES + pos] = s;
    }
}

// ---------------- MFMA GEMM: [N,128]bf16 @ Wt^T -> XL|XR bf16, XCD-chunked swizzle --------
// v14: staging via global_load_lds width=16 (async DMA, no VGPR round-trip).
//      LDS dest is linear per chunk (wave base + lane*16); the XOR swizzle is realized by
//      inverse-permuting the per-lane GLOBAL source column: k8 = (lane&15) ^ (row&15).
//      Padding rows clamp to row N-1 (A-row only feeds store-guarded C-rows).
__global__ __launch_bounds__(256) void gemm_mfma_kernel(
    const unsigned short* __restrict__ x,    // [N][128] bf16
    const unsigned short* __restrict__ Wt,   // [1024][128] bf16 (this layer-type)
    unsigned short* __restrict__ XL, unsigned short* __restrict__ XR)
{
    __shared__ unsigned short smem[32768];   // As 32K | Bs 32K, then C overlay
    unsigned short* As = smem;
    unsigned short* Bs = smem + 16384;
    const int tid = threadIdx.x;

    // bijective chunked XCD swizzle: 3128 % 8 == 0
    const int f    = blockIdx.x;
    const int g    = (f % 8) * GEMM_RB + (f / 8);
    const int rowb = g >> 3;
    const int colb = g & 7;
    const int nb = rowb * 128;
    const int cb = colb * 128;

    {
        const int wid  = tid >> 6;
        const int lane = tid & 63;
        // chunk c covers LDS bytes [c*1024, c*1024+1024) = rows 4c..4c+3 of the tile
        #pragma unroll
        for (int i = 0; i < 8; ++i) {
            const int c  = wid * 8 + i;              // 0..31
            const int r  = c * 4 + (lane >> 4);      // tile row this lane feeds
            const int k8 = (lane & 15) ^ (r & 15);   // inverse XOR swizzle on source col
            int node = nb + r;
            if (node >= N_NODES) node = N_NODES - 1; // clamp: garbage only in guarded C-rows
            gload_lds16(x + (size_t)node * H + k8 * 8, As + c * 512);
            gload_lds16(Wt + (size_t)(cb + r) * H + k8 * 8, Bs + c * 512);
        }
    }
    __syncthreads();

    const int wv = tid >> 6, lane = tid & 63;
    const int lm = lane & 15, kg = lane >> 4;
    const int wm = (wv & 1) * 64, wn = (wv >> 1) * 64;
    float4_t acc[4][4];
    #pragma unroll
    for (int i = 0; i < 4; ++i)
        #pragma unroll
        for (int j = 0; j < 4; ++j)
            acc[i][j] = (float4_t){0.f, 0.f, 0.f, 0.f};

    #pragma unroll
    for (int ks = 0; ks < 4; ++ks) {
        const int K8 = ks * 4 + kg;
        const int slot = (K8 ^ lm) * 8;
        short8_t a[4], b[4];
        #pragma unroll
        for (int i = 0; i < 4; ++i) {
            a[i] = *(const short8_t*)(As + (wm + i * 16 + lm) * H + slot);
            b[i] = *(const short8_t*)(Bs + (wn + i * 16 + lm) * H + slot);
        }
        #pragma unroll
        for (int i = 0; i < 4; ++i)
            #pragma unroll
            for (int j = 0; j < 4; ++j)
                acc[i][j] = __builtin_amdgcn_mfma_f32_16x16x32_bf16(a[i], b[j], acc[i][j], 0, 0, 0);
    }
    __syncthreads();

    unsigned short* Cs = smem;
    #pragma unroll
    for (int i = 0; i < 4; ++i) {
        int row0 = wm + i * 16 + kg * 4;
        #pragma unroll
        for (int j = 0; j < 4; ++j) {
            int col = wn + j * 16 + lm;
            #pragma unroll
            for (int r = 0; r < 4; ++r)
                Cs[(row0 + r) * 136 + col] = f2bf(acc[i][j][r]);
        }
    }
    __syncthreads();

    unsigned short* O = (colb < 4) ? XL : XR;
    const int cbase = (colb < 4) ? cb : cb - HH;
    #pragma unroll
    for (int it = 0; it < 8; ++it) {
        int c = it * 256 + tid;
        int r = c >> 4, k8 = (c & 15) * 8;
        int node = nb + r;
        if (node < N_NODES)
            *(uint4*)(O + (size_t)node * HH + cbase + k8) = *(const uint4*)(Cs + r * 136 + k8);
    }
}

// ---------------- per-dst flash-style GATv2 aggregation: 1 wave = 1 dst node (R9 proven) ---
__global__ __launch_bounds__(64) void aggregate_kernel(
    const unsigned short* __restrict__ XL, const unsigned short* __restrict__ XR,
    const float* __restrict__ att_t, const float* __restrict__ bias_t,
    const int* __restrict__ off, const int* __restrict__ csrc,
    float* __restrict__ xacc, int first,
    int fin, const float* __restrict__ x0, const float* __restrict__ skipw,
    int li, int last, unsigned short* __restrict__ xcurb, float* __restrict__ out)
{
    const int lane = threadIdx.x;
    const int d = blockIdx.x;
    if (d >= N_NODES) return;
    const int jb = lane * 8;
    const float L2E = 1.4426950408889634f;

    float2_t rv[4], c1[4], c2[4], acc2[4];
    {
        uint4 q = *(const uint4*)(XR + (size_t)d * HH + jb);
        unpack_pk(q, rv);
        float4 u0 = *(const float4*)(att_t + jb);
        float4 u1 = *(const float4*)(att_t + jb + 4);
        float av[8] = {u0.x, u0.y, u0.z, u0.w, u1.x, u1.y, u1.z, u1.w};
        #pragma unroll
        for (int u = 0; u < 4; ++u) {
            c1[u] = (float2_t){0.6f * L2E * av[2 * u], 0.6f * L2E * av[2 * u + 1]};
            c2[u] = (float2_t){0.4f * L2E * av[2 * u], 0.4f * L2E * av[2 * u + 1]};
            acc2[u] = (float2_t){0.f, 0.f};
        }
    }
    float den = 0.f;

    const int e0 = off[d];
    const int cnt = off[d + 1] - e0;

    uint4 q0 = make_uint4(0, 0, 0, 0), q1 = q0;
    unsigned s2 = 0, s3 = 0;
    if (cnt > 0) q0 = *(const uint4*)(XL + (size_t)((unsigned)csrc[e0])     * HH + jb);
    if (cnt > 1) q1 = *(const uint4*)(XL + (size_t)((unsigned)csrc[e0 + 1]) * HH + jb);
    if (cnt > 2) s2 = (unsigned)csrc[e0 + 2];
    if (cnt > 3) s3 = (unsigned)csrc[e0 + 3];

    int e = 0;
    for (; e + 1 < cnt; e += 2) {
        float2_t lv0[4], lv1[4];
        unpack_pk(q0, lv0);
        unpack_pk(q1, lv1);
        if (e + 2 < cnt) q0 = *(const uint4*)(XL + (size_t)s2 * HH + jb);
        if (e + 3 < cnt) q1 = *(const uint4*)(XL + (size_t)s3 * HH + jb);
        if (e + 4 < cnt) s2 = (unsigned)csrc[e0 + e + 4];
        if (e + 5 < cnt) s3 = (unsigned)csrc[e0 + e + 5];

        float2_t p20 = (float2_t){0.f, 0.f};
        float2_t p21 = (float2_t){0.f, 0.f};
        #pragma unroll
        for (int u = 0; u < 4; ++u) {
            float2_t m0 = pk_add(lv0[u], rv[u]);
            float2_t m1 = pk_add(lv1[u], rv[u]);
            float2_t a0 = pk_abs(m0);
            float2_t a1 = pk_abs(m1);
            p20 = pk_fma(c1[u], m0, p20);
            p21 = pk_fma(c1[u], m1, p21);
            p20 = pk_fma(c2[u], a0, p20);
            p21 = pk_fma(c2[u], a1, p21);
        }
        float p0 = row16_reduce(p20.x + p20.y);
        float p1 = row16_reduce(p21.x + p21.y);
        float w0 = fast_exp2(p0);
        float w1 = fast_exp2(p1);
        den += w0 + w1;
        float2_t w20 = (float2_t){w0, w0};
        float2_t w21 = (float2_t){w1, w1};
        #pragma unroll
        for (int u = 0; u < 4; ++u) {
            acc2[u] = pk_fma(w20, lv0[u], acc2[u]);
            acc2[u] = pk_fma(w21, lv1[u], acc2[u]);
        }
    }
    if (e < cnt) {
        float2_t lv0[4];
        unpack_pk(q0, lv0);
        float2_t p20 = (float2_t){0.f, 0.f};
        #pragma unroll
        for (int u = 0; u < 4; ++u) {
            float2_t m0 = pk_add(lv0[u], rv[u]);
            float2_t a0 = pk_abs(m0);
            p20 = pk_fma(c1[u], m0, p20);
            p20 = pk_fma(c2[u], a0, p20);
        }
        float p0 = row16_reduce(p20.x + p20.y);
        float w0 = fast_exp2(p0);
        den += w0;
        float2_t w20 = (float2_t){w0, w0};
        #pragma unroll
        for (int u = 0; u < 4; ++u) acc2[u] = pk_fma(w20, lv0[u], acc2[u]);
    }

    float inv = 1.f / (den + 1e-16f);
    float o[8];
    #pragma unroll
    for (int u = 0; u < 4; ++u) { o[2 * u] = acc2[u].x; o[2 * u + 1] = acc2[u].y; }
    #pragma unroll
    for (int u = 0; u < 8; ++u) {
        float v = o[u] * inv;
        v += __shfl_xor(v, 16);
        v += __shfl_xor(v, 32);
        o[u] = v * 0.25f;
    }
    if (lane < 16) {
        float* dst = xacc + (size_t)d * H + jb;
        #pragma unroll
        for (int u = 0; u < 8; ++u) o[u] += bias_t[jb + u];
        if (!fin) {
            float4 o0 = make_float4(o[0], o[1], o[2], o[3]);
            float4 o1 = make_float4(o[4], o[5], o[6], o[7]);
            if (first) {
                *(float4*)dst = o0;
                *(float4*)(dst + 4) = o1;
            } else {
                float4 c0 = *(const float4*)dst, c1v = *(const float4*)(dst + 4);
                o0.x += c0.x; o0.y += c0.y; o0.z += c0.z; o0.w += c0.w;
                o1.x += c1v.x; o1.y += c1v.y; o1.z += c1v.z; o1.w += c1v.w;
                *(float4*)dst = o0;
                *(float4*)(dst + 4) = o1;
            }
        } else {
            float sw = 1.f / (1.f + __expf(-skipw[li]));
            float4 c0 = *(const float4*)dst, c1v = *(const float4*)(dst + 4);
            float a0 = c0.x + o[0], a1 = c0.y + o[1], a2 = c0.z + o[2], a3 = c0.w + o[3];
            float a4 = c1v.x + o[4], a5 = c1v.y + o[5], a6 = c1v.z + o[6], a7 = c1v.w + o[7];
            const float* z = x0 + (size_t)d * H + jb;
            float4 z0 = *(const float4*)z, z1 = *(const float4*)(z + 4);
            float r0 = leaky(a0 * (1.f / 3.f)) + sw * z0.x;
            float r1 = leaky(a1 * (1.f / 3.f)) + sw * z0.y;
            float r2 = leaky(a2 * (1.f / 3.f)) + sw * z0.z;
            float r3 = leaky(a3 * (1.f / 3.f)) + sw * z0.w;
            float r4 = leaky(a4 * (1.f / 3.f)) + sw * z1.x;
            float r5 = leaky(a5 * (1.f / 3.f)) + sw * z1.y;
            float r6 = leaky(a6 * (1.f / 3.f)) + sw * z1.z;
            float r7 = leaky(a7 * (1.f / 3.f)) + sw * z1.w;
            if (last) {
                float* op = out + (size_t)d * H + jb;
                *(float4*)op       = make_float4(r0, r1, r2, r3);
                *(float4*)(op + 4) = make_float4(r4, r5, r6, r7);
            } else {
                unsigned int w0 = cvt_pk_bf16(r0, r1);
                unsigned int w1 = cvt_pk_bf16(r2, r3);
                unsigned int w2 = cvt_pk_bf16(r4, r5);
                unsigned int w3 = cvt_pk_bf16(r6, r7);
                *(uint4*)(xcurb + (size_t)d * H + jb) = make_uint4(w0, w1, w2, w3);
            }
        }
    }
}

extern "C" void kernel_launch(void* const* d_in, const int* in_sizes, int n_in,
                              void* d_out, int out_size, void* d_ws, size_t ws_size,
                              hipStream_t stream)
{
    const float* feat   = (const float*)d_in[0];
    const float* emb    = (const float*)d_in[1];
    const float* proj_w = (const float*)d_in[2];
    const float* proj_b = (const float*)d_in[3];
    const float* ln_g   = (const float*)d_in[4];
    const float* ln_b   = (const float*)d_in[5];
    const float* skip_w = (const float*)d_in[6];
    const float* Wl     = (const float*)d_in[7];
    const float* Wr     = (const float*)d_in[8];
    const float* att    = (const float*)d_in[9];
    const float* bias   = (const float*)d_in[10];
    const int*   esrc   = (const int*)d_in[11];
    const int*   edst   = (const int*)d_in[12];
    float* out = (float*)d_out;

    char* p = (char*)d_ws;
    auto alloc = [&](size_t bytes) -> char* {
        char* r = p; p += (bytes + 255) & ~(size_t)255; return r;
    };
    float* x0             = (float*)alloc((size_t)N_NODES * H * 4);
    unsigned short* xcurb = (unsigned short*)alloc((size_t)N_NODES * H * 2);
    unsigned short* XL    = (unsigned short*)alloc((size_t)N_NODES * HH * 2);
    unsigned short* XR    = (unsigned short*)alloc((size_t)N_NODES * HH * 2);
    unsigned short* Wt    = (unsigned short*)alloc((size_t)L_LAYERS * T_TYPES * 1024 * H * 2);
    unsigned short* pWtHi = (unsigned short*)alloc((size_t)H * F_IN * 2);
    unsigned short* pWtLo = (unsigned short*)alloc((size_t)H * F_IN * 2);
    int* off    = (int*)alloc((size_t)T_TYPES * NOFF * 4);
    int* cursor = (int*)alloc((size_t)T_TYPES * N_NODES * 4);
    int* csrc   = (int*)alloc((size_t)T_TYPES * E_EDGES * 4);
    int* bsum   = (int*)alloc((size_t)T_TYPES * NBLK * 4);
    int* eflag  = (int*)alloc(256);
    float* xacc = out;  // scratch accumulator aliases d_out

    // init-phase scratch aliases the (still-dead) XL/XR regions
    float* proj          = (float*)XL;                                   // 25.6 MB <= 51.2
    unsigned short* fHi  = XR;                                           // 25.6 MB
    unsigned short* fLo  = XR + (size_t)N_NODES * F_IN;                  // 25.6 MB

    hipMemsetAsync(cursor, 0, (size_t)T_TYPES * N_NODES * 4, stream);

    // prologue: 5 dispatches — independent chains co-dispatched via blockIdx ranges
    combo_a_kernel<<<CA_TOTAL, 256, 0, stream>>>(feat, fHi, fLo, Wl, Wr, Wt,
                                                 proj_w, pWtHi, pWtLo, edst, eflag);
    combo_b_kernel<<<CB_TOTAL, 256, 0, stream>>>(fHi, fLo, pWtHi, pWtLo, proj,
                                                 edst, cursor, eflag);
    combo_c_kernel<<<CC_TOTAL, 256, 0, stream>>>(proj, emb, proj_b, ln_g, ln_b,
                                                 x0, xcurb, cursor, bsum);
    scan_c2_kernel<<<T_TYPES * NBLK, 256, 0, stream>>>(cursor, bsum, off, cursor);
    scatter_kernel<<<(T_TYPES * E_EDGES + 255) / 256, 256, 0, stream>>>(esrc, edst, cursor, csrc, eflag);

    for (int i = 0; i < L_LAYERS; ++i) {
        for (int t = 0; t < T_TYPES; ++t) {
            const int lt = i * T_TYPES + t;
            const unsigned short* wt = Wt + (size_t)lt * 1024 * H;
            const float* at = att + (size_t)lt * HEADS * H;
            const float* bi = bias + (size_t)lt * H;
            gemm_mfma_kernel<<<GEMM_GRID, 256, 0, stream>>>(xcurb, wt, XL, XR);
            aggregate_kernel<<<N_NODES, 64, 0, stream>>>(
                XL, XR, at, bi, off + t * NOFF, csrc + (size_t)t * E_EDGES,
                xacc, (t == 0) ? 1 : 0,
                (t == T_TYPES - 1) ? 1 : 0, x0, skip_w, i,
                (i == L_LAYERS - 1) ? 1 : 0, xcurb, out);
        }
    }
}